// Round 10
// baseline (381.992 us; speedup 1.0000x reference)
//
#include <hip/hip_runtime.h>
#include <hip/hip_bf16.h>
#include <cfloat>
#include <stdint.h>

#define EPS 1e-5f
constexpr int Dd = 512, Tt = 1024, Kk = 8192;
constexpr int Nq = 16 * 1024;
constexpr float TAU = 1.5f;   // ~7 sigma of 1-product bf16 error + key quant

typedef __bf16 bf16x8 __attribute__((ext_vector_type(8)));
typedef float  f32x4  __attribute__((ext_vector_type(4)));
typedef unsigned long long u64;

union Pack8 { __bf16 h[8]; int4 v; };

__device__ __forceinline__ void gld16(const void* g, void* l) {
    __builtin_amdgcn_global_load_lds(
        (const __attribute__((address_space(1))) uint32_t*)g,
        (__attribute__((address_space(3))) uint32_t*)l, 16, 0, 0);
}

// ---- monotone fp32 -> u32 key helpers --------------------------------------
__device__ __forceinline__ unsigned monokey(float s) {
    unsigned b = __float_as_uint(s);
    return b ^ ((unsigned)((int)b >> 31) | 0x80000000u);
}
__device__ __forceinline__ float unmono(unsigned u) {
    u = (u & 0x80000000u) ? (u ^ 0x80000000u) : ~u;
    return __uint_as_float(u);
}

// ---- sorted-pair / sorted-quad merges --------------------------------------
__device__ __forceinline__ void merge2u(unsigned& a1, unsigned& a2, unsigned b1, unsigned b2) {
    unsigned c1 = min(a1, b1);
    unsigned c2 = min(max(a1, b1), min(a2, b2));
    a1 = c1; a2 = c2;
}
__device__ __forceinline__ u64 umin64(u64 a, u64 b) { return a < b ? a : b; }
__device__ __forceinline__ u64 umax64(u64 a, u64 b) { return a > b ? a : b; }
__device__ __forceinline__ void merge4q(u64& a1, u64& a2, u64& a3, u64& a4,
                                        u64 b1, u64 b2, u64 b3, u64 b4) {
    u64 c1 = umin64(a1, b1);
    u64 c2 = umin64(umin64(a2, b2), umax64(a1, b1));
    u64 c3 = umin64(umin64(a3, b3), umin64(umax64(a2, b1), umax64(a1, b2)));
    u64 c4 = umin64(umin64(a4, b4), umin64(umax64(a3, b1), umax64(a1, b3)));
    c4 = umin64(c4, umax64(a2, b2));
    a1 = c1; a2 = c2; a3 = c3; a4 = c4;
}
__device__ __forceinline__ u64 shflx64(u64 v, int m) {
    int lo = __shfl_xor((int)(unsigned)v, m, 64);
    int hi = __shfl_xor((int)(v >> 32), m, 64);
    return ((u64)(unsigned)hi << 32) | (unsigned)lo;
}

// ---------------- P1: x (B,D,T) -> Xh bf16 + Xf fp32, both (B*T, D) ---------
__global__ __launch_bounds__(256) void split_x_kernel(const float* __restrict__ x,
                                                      ushort* __restrict__ Xh,
                                                      float* __restrict__ Xf,
                                                      int* __restrict__ cnt) {
    if (blockIdx.x == 0 && threadIdx.x < 2) cnt[threadIdx.x] = 0;
    __shared__ float Ls[64][68];
    const int tid = threadIdx.x, bid = blockIdx.x;
    const int b  = bid >> 7;
    const int d0 = ((bid >> 4) & 7) * 64;
    const int t0 = (bid & 15) * 64;
    const float* xb = x + ((size_t)b * Dd + d0) * Tt + t0;
#pragma unroll
    for (int it = 0; it < 4; ++it) {
        int s = it * 256 + tid;
        int d = s >> 4, c = (s & 15) * 4;
        float4 g = *(const float4*)(xb + (size_t)d * Tt + c);
        *(float4*)&Ls[d][c] = g;
    }
    __syncthreads();
    const int t = tid >> 2;
    const int dseg = (tid & 3) * 16;
    Pack8 ph[2];
    float vf[16];
#pragma unroll
    for (int dd = 0; dd < 16; ++dd) {
        float v = Ls[dseg + dd][t];
        vf[dd] = v;
        ph[dd >> 3].h[dd & 7] = (__bf16)v;
    }
    size_t base = ((size_t)(b * Tt + t0 + t)) * Dd + d0 + dseg;
    *(int4*)(Xh + base)     = ph[0].v;
    *(int4*)(Xh + base + 8) = ph[1].v;
#pragma unroll
    for (int g = 0; g < 4; ++g)
        *(float4*)(Xf + base + g * 4) = make_float4(vf[g*4], vf[g*4+1], vf[g*4+2], vf[g*4+3]);
}

// ---------------- P2: emb=es/clip(u) -> Eh bf16 + embf fp32 + e2 ------------
__global__ __launch_bounds__(256) void split_e_kernel(const float* __restrict__ es,
                                                      const float* __restrict__ usage,
                                                      ushort* __restrict__ Eh,
                                                      float* __restrict__ embf,
                                                      double* __restrict__ e2d,
                                                      float* __restrict__ e2f) {
    const int wave = threadIdx.x >> 6, lane = threadIdx.x & 63;
    const int k = blockIdx.x * 4 + wave;
    const float uc = fmaxf(usage[k], EPS);
    const float* row = es + (size_t)k * Dd;
    const int d = lane * 8;
    float4 a = *(const float4*)(row + d);
    float4 c = *(const float4*)(row + d + 4);
    float ef[8] = {a.x/uc, a.y/uc, a.z/uc, a.w/uc, c.x/uc, c.y/uc, c.z/uc, c.w/uc};
    Pack8 ph;
    double e2 = 0.0;
#pragma unroll
    for (int j = 0; j < 8; ++j) {
        ph.h[j] = (__bf16)ef[j];
        e2 = fma((double)ef[j], (double)ef[j], e2);
    }
    size_t base = (size_t)k * Dd + d;
    *(int4*)(Eh + base) = ph.v;
    *(float4*)(embf + base)     = make_float4(ef[0], ef[1], ef[2], ef[3]);
    *(float4*)(embf + base + 4) = make_float4(ef[4], ef[5], ef[6], ef[7]);
#pragma unroll
    for (int off = 32; off >= 1; off >>= 1) e2 += __shfl_down(e2, off, 64);
    if (lane == 0) { e2d[k] = e2; e2f[k] = (float)e2; }
}

// ---------------- main GEMM: 256x256 tile, BK=64, cross-phase pipeline ------
// Round-6 verified kernel (139.5 us, MfmaUtil 44%, conflicts 0), now launched
// as TWO 1024-block dispatches (mb halves) so other kernels surface in the
// rocprof top-5 (diagnostic round). wgbase selects the supertile half.
__device__ __forceinline__ void stageA2(const ushort* __restrict__ Xh, char* buf,
                                        int m0, int d0, int tid, int j0) {
#pragma unroll
    for (int j = 0; j < 2; ++j) {
        int s = (j0 + j) * 512 + tid;
        int row = s >> 3;
        int clog = (s & 7) ^ (row & 7);            // inverse swizzle on SOURCE
        gld16(Xh + (size_t)(m0 + row) * Dd + d0 + clog * 8, buf + s * 16);
    }
}
__device__ __forceinline__ void stageB2(const ushort* __restrict__ Eh, char* buf,
                                        int n0, int d0, int tid, int j0) {
#pragma unroll
    for (int j = 0; j < 2; ++j) {
        int s = (j0 + j) * 512 + tid;
        int row = s >> 3;
        int clog = (s & 7) ^ (row & 7);
        gld16(Eh + (size_t)(n0 + row) * Dd + d0 + clog * 8, buf + 32768 + s * 16);
    }
}

#define SB() __builtin_amdgcn_sched_barrier(0)

__global__ __launch_bounds__(512) void gemm_kernel(const ushort* __restrict__ Xh,
                                                   const ushort* __restrict__ Eh,
                                                   const float* __restrict__ e2f,
                                                   uint2* __restrict__ colres,
                                                   int wgbase) {
    __shared__ int4 ldsbuf[8192];   // 128 KiB
    char* lds = (char*)ldsbuf;

    const int tid = threadIdx.x;
    // per-launch grid 1024; XCD chunks of 128 (4 supertiles each, 3MB L2-fit).
    int wg = blockIdx.x;
    int wgid = wgbase + (wg & 7) * 128 + (wg >> 3);
    int st = wgid >> 5, u = wgid & 31;
    int mb = (st >> 3) * 8 + (u & 7);
    int nb = (st & 7) * 4 + (u >> 3);
    const int m0 = mb * 256, n0 = nb * 256;

    const int wave = tid >> 6, lane = tid & 63;
    const int wm = wave >> 1, wn = wave & 1;
    const int mw = wm * 64, nw = wn * 128;
    const int fm = lane & 15, fq = lane >> 4;
    const int fm7 = fm & 7;
    const int x0 = (fq ^ fm7) * 16;          // kk=0 swizzled chunk byte offset
    const int x1 = ((4 + fq) ^ fm7) * 16;    // kk=1
    const int pao = (mw + fm) * 128;
    const int pbo = 32768 + (nw + fm) * 128;

    f32x4 acc[8][4] = {};
    bf16x8 a0[4], a1[4], bl0[4], bh0[4], bl1[4], bh1[4];

    // prologue: tile0 full + tile1's A1; vmcnt(2) keeps A1(1) in flight
    stageA2(Xh, lds, m0, 0, tid, 0);
    stageA2(Xh, lds, m0, 0, tid, 2);
    stageB2(Eh, lds, n0, 0, tid, 0);
    stageB2(Eh, lds, n0, 0, tid, 2);
    stageA2(Xh, lds + 65536, m0, 64, tid, 0);
    asm volatile("s_waitcnt vmcnt(2)" ::: "memory");
    __builtin_amdgcn_s_barrier();
    SB();
    // S1(0) reads
#pragma unroll
    for (int i = 0; i < 4; ++i) a0[i]  = *(const bf16x8*)(lds + pao + i * 2048 + x0);
#pragma unroll
    for (int i = 0; i < 4; ++i) bl0[i] = *(const bf16x8*)(lds + pbo + i * 2048 + x0);
    SB();

    for (int t = 0; t < 8; ++t) {
        char* bufc = lds + (t & 1) * 65536;
        char* bufn = lds + ((t + 1) & 1) * 65536;
        const char* pA = bufc + pao;
        const char* pB = bufc + pbo;
        const int d1 = (t + 1) * 64, d2 = (t + 2) * 64;

        // ---- P1: issue S2 reads | stage A2(t+1) | MFMA S1 ------------------
#pragma unroll
        for (int i = 0; i < 4; ++i) bh0[i] = *(const bf16x8*)(pB + 8192 + i * 2048 + x0);
        SB();
        if (t + 1 < 8) stageA2(Xh, bufn, m0, d1, tid, 2);
        SB();
        asm volatile("s_waitcnt lgkmcnt(4)" ::: "memory");   // S1 done
        SB();
        __builtin_amdgcn_s_setprio(1);
#pragma unroll
        for (int i = 0; i < 4; ++i)
#pragma unroll
            for (int j = 0; j < 4; ++j)
                acc[i][j] = __builtin_amdgcn_mfma_f32_16x16x32_bf16(bl0[i], a0[j], acc[i][j], 0, 0, 0);
        __builtin_amdgcn_s_setprio(0);
        SB();
        __builtin_amdgcn_s_barrier();

        // ---- P2: issue S3 reads | stage B1(t+1) | MFMA S2 ------------------
#pragma unroll
        for (int i = 0; i < 4; ++i) a1[i]  = *(const bf16x8*)(pA + i * 2048 + x1);
#pragma unroll
        for (int i = 0; i < 4; ++i) bl1[i] = *(const bf16x8*)(pB + i * 2048 + x1);
        SB();
        if (t + 1 < 8) stageB2(Eh, bufn, n0, d1, tid, 0);
        SB();
        asm volatile("s_waitcnt lgkmcnt(8)" ::: "memory");   // S2 done
        SB();
        __builtin_amdgcn_s_setprio(1);
#pragma unroll
        for (int i = 0; i < 4; ++i)
#pragma unroll
            for (int j = 0; j < 4; ++j)
                acc[i + 4][j] = __builtin_amdgcn_mfma_f32_16x16x32_bf16(bh0[i], a0[j], acc[i + 4][j], 0, 0, 0);
        __builtin_amdgcn_s_setprio(0);
        SB();
        __builtin_amdgcn_s_barrier();

        // ---- P3: issue S4 reads | stage B2(t+1) | MFMA S3 ------------------
#pragma unroll
        for (int i = 0; i < 4; ++i) bh1[i] = *(const bf16x8*)(pB + 8192 + i * 2048 + x1);
        SB();
        if (t + 1 < 8) stageB2(Eh, bufn, n0, d1, tid, 2);
        SB();
        asm volatile("s_waitcnt lgkmcnt(4)" ::: "memory");   // S3 done
        SB();
        __builtin_amdgcn_s_setprio(1);
#pragma unroll
        for (int i = 0; i < 4; ++i)
#pragma unroll
            for (int j = 0; j < 4; ++j)
                acc[i][j] = __builtin_amdgcn_mfma_f32_16x16x32_bf16(bl1[i], a1[j], acc[i][j], 0, 0, 0);
        __builtin_amdgcn_s_setprio(0);
        SB();
        __builtin_amdgcn_s_barrier();

        // ---- P4: drain reads | barrier | stage A1(t+2) into bufc | MFMA S4 -
        asm volatile("s_waitcnt lgkmcnt(0)" ::: "memory");   // S4 done
        SB();
        __builtin_amdgcn_s_barrier();   // all waves' bufc reads complete
        if (t + 2 < 8) stageA2(Xh, bufc, m0, d2, tid, 0);
        SB();
        __builtin_amdgcn_s_setprio(1);
#pragma unroll
        for (int i = 0; i < 4; ++i)
#pragma unroll
            for (int j = 0; j < 4; ++j)
                acc[i + 4][j] = __builtin_amdgcn_mfma_f32_16x16x32_bf16(bh1[i], a1[j], acc[i + 4][j], 0, 0, 0);
        __builtin_amdgcn_s_setprio(0);
        SB();

        // ---- boundary: counted vmcnt + barrier + S1(t+1) reads -------------
        if (t < 7) {
            if (t < 6) { asm volatile("s_waitcnt vmcnt(2)" ::: "memory"); }
            else       { asm volatile("s_waitcnt vmcnt(0)" ::: "memory"); }
            SB();
            __builtin_amdgcn_s_barrier();
            SB();
            const char* pAn = bufn + pao;
            const char* pBn = bufn + pbo;
#pragma unroll
            for (int i = 0; i < 4; ++i) a0[i]  = *(const bf16x8*)(pAn + i * 2048 + x0);
#pragma unroll
            for (int i = 0; i < 4; ++i) bl0[i] = *(const bf16x8*)(pBn + i * 2048 + x0);
            SB();
        }
    }

    // ---- epilogue: top-2 per (m-row, 128-n-block), n lane-local ------------
    // acc[ni][mj][r]: n = nw + ni*16 + fq*4 + r ; m = mw + mj*16 + fm
    float4 e2v[8];
#pragma unroll
    for (int ni = 0; ni < 8; ++ni)
        e2v[ni] = *(const float4*)(e2f + n0 + nw + ni * 16 + fq * 4);

    const int cb = (n0 + nw) >> 7;   // 128-col block index (0..63)
#pragma unroll
    for (int mj = 0; mj < 4; ++mj) {
        unsigned s1 = 0xFFFFFFFFu, s2 = 0xFFFFFFFFu;
#pragma unroll
        for (int ni = 0; ni < 8; ++ni) {
            unsigned k0 = (monokey(fmaf(-2.0f, acc[ni][mj][0], e2v[ni].x)) & 0xFFFFFF80u) | (unsigned)(ni * 16 + fq * 4 + 0);
            unsigned k1 = (monokey(fmaf(-2.0f, acc[ni][mj][1], e2v[ni].y)) & 0xFFFFFF80u) | (unsigned)(ni * 16 + fq * 4 + 1);
            unsigned k2 = (monokey(fmaf(-2.0f, acc[ni][mj][2], e2v[ni].z)) & 0xFFFFFF80u) | (unsigned)(ni * 16 + fq * 4 + 2);
            unsigned k3 = (monokey(fmaf(-2.0f, acc[ni][mj][3], e2v[ni].w)) & 0xFFFFFF80u) | (unsigned)(ni * 16 + fq * 4 + 3);
            unsigned lo01 = min(k0, k1), hi01 = max(k0, k1);
            unsigned lo23 = min(k2, k3), hi23 = max(k2, k3);
            unsigned p1 = min(lo01, lo23);
            unsigned p2 = min(max(lo01, lo23), min(hi01, hi23));
            merge2u(s1, s2, p1, p2);
        }
        // reduce across fq groups (lanes fm, fm+16, fm+32, fm+48)
#pragma unroll
        for (int stg = 16; stg <= 32; stg <<= 1) {
            unsigned b1 = __shfl_xor(s1, stg, 64);
            unsigned b2 = __shfl_xor(s2, stg, 64);
            merge2u(s1, s2, b1, b2);
        }
        if (lane < 16)
            colres[(size_t)(m0 + mw + mj * 16 + lane) * 64 + cb] = make_uint2(s1, s2);
    }
}

// ------- merge: global top-4 of block-pairs + collision ballot; tiering -----
__global__ __launch_bounds__(256) void merge_kernel(const uint2* __restrict__ colres,
                                                    float* __restrict__ out,
                                                    int* __restrict__ cnt,
                                                    int* __restrict__ queueC,
                                                    int* __restrict__ queueF) {
    const int wave = threadIdx.x >> 6, lane = threadIdx.x & 63;
    const int row = blockIdx.x * 4 + wave;
    uint2 q = colres[(size_t)row * 64 + lane];
    const unsigned nb128 = (unsigned)(lane * 128);
    u64 a1 = ((u64)(q.x & 0xFFFFFF80u) << 32) | (nb128 + (q.x & 127u));
    u64 a2 = ((u64)(q.y & 0xFFFFFF80u) << 32) | (nb128 + (q.y & 127u));
    u64 a3 = ~0ull, a4 = ~0ull;
#pragma unroll
    for (int st = 1; st < 64; st <<= 1)
        merge4q(a1, a2, a3, a4, shflx64(a1, st), shflx64(a2, st), shflx64(a3, st), shflx64(a4, st));
    // all lanes hold the global top-4 now
    float v1 = unmono((unsigned)(a1 >> 32));
    // block-collision: this lane's block has 2+ entries within TAU of global min
    u64 coll = __ballot(unmono(q.y) < v1 + TAU);
    if (lane == 0) {
        float v2 = unmono((unsigned)(a2 >> 32));
        float v4 = unmono((unsigned)(a4 >> 32));
        int i1 = (int)(unsigned)a1;
        out[row] = (float)i1;
        if (coll != 0ull || (v4 - v1 < TAU)) {   // candidate set may be incomplete
            int p = atomicAdd(&cnt[1], 1);
            queueF[p] = row;
        } else if (v2 - v1 < TAU) {              // winner provably in {i1..i4}
            int p = atomicAdd(&cnt[0], 1);
            queueC[p * 5]     = row;
            queueC[p * 5 + 1] = i1;
            queueC[p * 5 + 2] = (int)(unsigned)a2;
            queueC[p * 5 + 3] = (int)(unsigned)a3;
            queueC[p * 5 + 4] = (int)(unsigned)a4;
        }
    }
}

// ------- candidate rescore: exact fp64 on {i1..i4}, one wave per query ------
__global__ __launch_bounds__(256) void cand_kernel(const float* __restrict__ Xf,
                                                   const float* __restrict__ embf,
                                                   const double* __restrict__ e2d,
                                                   const int* __restrict__ cnt,
                                                   const int* __restrict__ queueC,
                                                   float* __restrict__ out) {
    const int wv = (blockIdx.x << 2) | (threadIdx.x >> 6);
    const int lane = threadIdx.x & 63;
    const int n = cnt[0];
    for (int p = wv; p < n; p += gridDim.x * 4) {
        int row = queueC[p * 5];
        int ci[4] = {queueC[p*5+1], queueC[p*5+2], queueC[p*5+3], queueC[p*5+4]};
        const float* xr = Xf + (size_t)row * Dd + lane * 8;
        float4 xa = *(const float4*)xr;
        float4 xb = *(const float4*)(xr + 4);
        double s[4] = {0.0, 0.0, 0.0, 0.0};
#pragma unroll
        for (int c = 0; c < 4; ++c) {
            const float* er = embf + (size_t)ci[c] * Dd + lane * 8;
            float4 ea = *(const float4*)er;
            float4 eb = *(const float4*)(er + 4);
            double t = 0.0;
            t = fma((double)xa.x, (double)ea.x, t);
            t = fma((double)xa.y, (double)ea.y, t);
            t = fma((double)xa.z, (double)ea.z, t);
            t = fma((double)xa.w, (double)ea.w, t);
            t = fma((double)xb.x, (double)eb.x, t);
            t = fma((double)xb.y, (double)eb.y, t);
            t = fma((double)xb.z, (double)eb.z, t);
            t = fma((double)xb.w, (double)eb.w, t);
            s[c] = t;
        }
#pragma unroll
        for (int off = 32; off >= 1; off >>= 1) {
#pragma unroll
            for (int c = 0; c < 4; ++c) s[c] += __shfl_down(s[c], off, 64);
        }
        if (lane == 0) {
            double bv = DBL_MAX; int bi = 0x7fffffff;
#pragma unroll
            for (int c = 0; c < 4; ++c) {
                double dv = fma(-2.0, s[c], e2d[ci[c]]);
                if (dv < bv || (dv == bv && ci[c] < bi)) { bv = dv; bi = ci[c]; }
            }
            out[row] = (float)bi;
        }
    }
}

// ---------------- rare full exact scan: 16 chunks x 512 clusters per query --
__global__ __launch_bounds__(256) void fscan_kernel(const float* __restrict__ Xf,
                                                    const float* __restrict__ embf,
                                                    const double* __restrict__ e2d,
                                                    const int* __restrict__ cnt,
                                                    const int* __restrict__ queueF,
                                                    double* __restrict__ fbv,
                                                    int* __restrict__ fbi) {
    __shared__ float xs[512];
    __shared__ double sv[256];
    __shared__ int si[256];
    const int tid = threadIdx.x;
    const int ntask = cnt[1] * 16;
    for (int task = blockIdx.x; task < ntask; task += gridDim.x) {
        int qi = task >> 4, ch = task & 15;
        int row = queueF[qi];
        __syncthreads();
        for (int d = tid; d < Dd; d += 256)
            xs[d] = Xf[(size_t)row * Dd + d];
        __syncthreads();
        double bv = DBL_MAX; int bi = 0x7fffffff;
#pragma unroll
        for (int c = 0; c < 2; ++c) {
            int k = ch * 512 + c * 256 + tid;
            const float* er = embf + (size_t)k * Dd;
            double a0 = 0, a1 = 0, a2 = 0, a3 = 0;
            for (int d = 0; d < Dd; d += 4) {
                float4 e = *(const float4*)(er + d);
                float4 xv = *(const float4*)&xs[d];
                a0 = fma((double)e.x, (double)xv.x, a0);
                a1 = fma((double)e.y, (double)xv.y, a1);
                a2 = fma((double)e.z, (double)xv.z, a2);
                a3 = fma((double)e.w, (double)xv.w, a3);
            }
            double s = fma(-2.0, (a0 + a1) + (a2 + a3), e2d[k]);
            if (s < bv || (s == bv && k < bi)) { bv = s; bi = k; }
        }
        sv[tid] = bv; si[tid] = bi;
        __syncthreads();
        for (int off = 128; off > 0; off >>= 1) {
            if (tid < off) {
                if (sv[tid + off] < sv[tid] ||
                    (sv[tid + off] == sv[tid] && si[tid + off] < si[tid])) {
                    sv[tid] = sv[tid + off]; si[tid] = si[tid + off];
                }
            }
            __syncthreads();
        }
        if (tid == 0) { fbv[task] = sv[0]; fbi[task] = si[0]; }
    }
}

__global__ void fmerge_kernel(const int* __restrict__ cnt,
                              const int* __restrict__ queueF,
                              const double* __restrict__ fbv,
                              const int* __restrict__ fbi,
                              float* __restrict__ out) {
    const int nF = cnt[1];
    for (int qi = blockIdx.x * 256 + threadIdx.x; qi < nF; qi += gridDim.x * 256) {
        double bv = DBL_MAX; int bi = 0x7fffffff;
        for (int c = 0; c < 16; ++c) {
            double v = fbv[qi * 16 + c]; int i = fbi[qi * 16 + c];
            if (v < bv || (v == bv && i < bi)) { bv = v; bi = i; }
        }
        out[queueF[qi]] = (float)bi;
    }
}

// ---------------- gather quantized rows, coalesced along t ------------------
__global__ __launch_bounds__(256) void gather_kernel(const float* __restrict__ embf,
                                                     float* __restrict__ out) {
    __shared__ int cs[64];
    const int tid = threadIdx.x;
    const int m0 = blockIdx.x * 64;
    const int b = m0 >> 10;
    const int t0 = m0 & (Tt - 1);
    if (tid < 64) cs[tid] = (int)out[m0 + tid];
    __syncthreads();
    const int tq = tid & 63;
    const int dg = tid >> 6;
    const int c = cs[tq];
    const float* row = embf + (size_t)c * Dd;   // embf == exact fp32 es/clip(u)
    float* ob = out + Nq + (size_t)b * Dd * Tt + t0 + tq;
#pragma unroll 4
    for (int d = dg * 128; d < dg * 128 + 128; ++d)
        ob[(size_t)d * Tt] = row[d];
}

extern "C" void kernel_launch(void* const* d_in, const int* in_sizes, int n_in,
                              void* d_out, int out_size, void* d_ws, size_t ws_size,
                              hipStream_t stream) {
    const float* x     = (const float*)d_in[0];
    const float* es    = (const float*)d_in[1];
    const float* usage = (const float*)d_in[2];
    float* out = (float*)d_out;

    char* w = (char*)d_ws;
    ushort* Xh = (ushort*)w;   w += (size_t)Nq * Dd * 2;      // 16 MB
    ushort* Eh = (ushort*)w;   w += (size_t)Kk * Dd * 2;      //  8 MB
    float*  Xf = (float*)w;    w += (size_t)Nq * Dd * 4;      // 32 MB
    float*  embf = (float*)w;  w += (size_t)Kk * Dd * 4;      // 16 MB
    double* e2d = (double*)w;  w += (size_t)Kk * 8;
    float*  e2f = (float*)w;   w += (size_t)Kk * 4;
    uint2* colres = (uint2*)w; w += (size_t)Nq * 64 * 8;      // 8.4 MB
    int* cnt = (int*)w;        w += 256;
    int* queueC = (int*)w;     w += (size_t)Nq * 5 * 4;
    int* queueF = (int*)w;     w += (size_t)Nq * 4;
    // fbv/fbi alias Xh (dead after gemm_kernel; fscan runs strictly later)
    double* fbv = (double*)Xh;
    int*    fbi = (int*)((char*)Xh + 4 * 1024 * 1024);

    split_x_kernel<<<2048, 256, 0, stream>>>(x, Xh, Xf, cnt);
    split_e_kernel<<<Kk / 4, 256, 0, stream>>>(es, usage, Eh, embf, e2d, e2f);
    gemm_kernel<<<1024, 512, 0, stream>>>(Xh, Eh, e2f, colres, 0);
    gemm_kernel<<<1024, 512, 0, stream>>>(Xh, Eh, e2f, colres, 1024);
    merge_kernel<<<Nq / 4, 256, 0, stream>>>(colres, out, cnt, queueC, queueF);
    cand_kernel<<<256, 256, 0, stream>>>(Xf, embf, e2d, cnt, queueC, out);
    fscan_kernel<<<256, 256, 0, stream>>>(Xf, embf, e2d, cnt, queueF, fbv, fbi);
    fmerge_kernel<<<64, 256, 0, stream>>>(cnt, queueF, fbv, fbi, out);
    gather_kernel<<<Nq / 64, 256, 0, stream>>>(embf, out);
}

// Round 11
// 356.477 us; speedup vs baseline: 1.0716x; 1.0716x over previous
//
#include <hip/hip_runtime.h>
#include <hip/hip_bf16.h>
#include <cfloat>
#include <stdint.h>

#define EPS 1e-5f
constexpr int Dd = 512, Tt = 1024, Kk = 8192;
constexpr int Nq = 16 * 1024;
constexpr float TAU = 1.5f;   // ~7 sigma of 1-product bf16 error + key quant

typedef __bf16 bf16x8 __attribute__((ext_vector_type(8)));
typedef float  f32x4  __attribute__((ext_vector_type(4)));
typedef unsigned long long u64;

union Pack8 { __bf16 h[8]; int4 v; };

__device__ __forceinline__ void gld16(const void* g, void* l) {
    __builtin_amdgcn_global_load_lds(
        (const __attribute__((address_space(1))) uint32_t*)g,
        (__attribute__((address_space(3))) uint32_t*)l, 16, 0, 0);
}

// ---- monotone fp32 -> u32 key helpers --------------------------------------
__device__ __forceinline__ unsigned monokey(float s) {
    unsigned b = __float_as_uint(s);
    return b ^ ((unsigned)((int)b >> 31) | 0x80000000u);
}
__device__ __forceinline__ float unmono(unsigned u) {
    u = (u & 0x80000000u) ? (u ^ 0x80000000u) : ~u;
    return __uint_as_float(u);
}

// ---- sorted-pair / sorted-quad merges --------------------------------------
__device__ __forceinline__ void merge2u(unsigned& a1, unsigned& a2, unsigned b1, unsigned b2) {
    unsigned c1 = min(a1, b1);
    unsigned c2 = min(max(a1, b1), min(a2, b2));
    a1 = c1; a2 = c2;
}
__device__ __forceinline__ u64 umin64(u64 a, u64 b) { return a < b ? a : b; }
__device__ __forceinline__ u64 umax64(u64 a, u64 b) { return a > b ? a : b; }
__device__ __forceinline__ void merge4q(u64& a1, u64& a2, u64& a3, u64& a4,
                                        u64 b1, u64 b2, u64 b3, u64 b4) {
    u64 c1 = umin64(a1, b1);
    u64 c2 = umin64(umin64(a2, b2), umax64(a1, b1));
    u64 c3 = umin64(umin64(a3, b3), umin64(umax64(a2, b1), umax64(a1, b2)));
    u64 c4 = umin64(umin64(a4, b4), umin64(umax64(a3, b1), umax64(a1, b3)));
    c4 = umin64(c4, umax64(a2, b2));
    a1 = c1; a2 = c2; a3 = c3; a4 = c4;
}
__device__ __forceinline__ u64 shflx64(u64 v, int m) {
    int lo = __shfl_xor((int)(unsigned)v, m, 64);
    int hi = __shfl_xor((int)(v >> 32), m, 64);
    return ((u64)(unsigned)hi << 32) | (unsigned)lo;
}

// ---------------- P1: x (B,D,T) -> Xh bf16 + Xf fp32, both (B*T, D) ---------
__global__ __launch_bounds__(256) void split_x_kernel(const float* __restrict__ x,
                                                      ushort* __restrict__ Xh,
                                                      float* __restrict__ Xf,
                                                      int* __restrict__ cnt) {
    if (blockIdx.x == 0 && threadIdx.x < 2) cnt[threadIdx.x] = 0;
    __shared__ float Ls[64][68];
    const int tid = threadIdx.x, bid = blockIdx.x;
    const int b  = bid >> 7;
    const int d0 = ((bid >> 4) & 7) * 64;
    const int t0 = (bid & 15) * 64;
    const float* xb = x + ((size_t)b * Dd + d0) * Tt + t0;
#pragma unroll
    for (int it = 0; it < 4; ++it) {
        int s = it * 256 + tid;
        int d = s >> 4, c = (s & 15) * 4;
        float4 g = *(const float4*)(xb + (size_t)d * Tt + c);
        *(float4*)&Ls[d][c] = g;
    }
    __syncthreads();
    const int t = tid >> 2;
    const int dseg = (tid & 3) * 16;
    Pack8 ph[2];
    float vf[16];
#pragma unroll
    for (int dd = 0; dd < 16; ++dd) {
        float v = Ls[dseg + dd][t];
        vf[dd] = v;
        ph[dd >> 3].h[dd & 7] = (__bf16)v;
    }
    size_t base = ((size_t)(b * Tt + t0 + t)) * Dd + d0 + dseg;
    *(int4*)(Xh + base)     = ph[0].v;
    *(int4*)(Xh + base + 8) = ph[1].v;
#pragma unroll
    for (int g = 0; g < 4; ++g)
        *(float4*)(Xf + base + g * 4) = make_float4(vf[g*4], vf[g*4+1], vf[g*4+2], vf[g*4+3]);
}

// ---------------- P2: emb=es/clip(u) -> Eh bf16 + embf fp32 + e2 ------------
__global__ __launch_bounds__(256) void split_e_kernel(const float* __restrict__ es,
                                                      const float* __restrict__ usage,
                                                      ushort* __restrict__ Eh,
                                                      float* __restrict__ embf,
                                                      double* __restrict__ e2d,
                                                      float* __restrict__ e2f) {
    const int wave = threadIdx.x >> 6, lane = threadIdx.x & 63;
    const int k = blockIdx.x * 4 + wave;
    const float uc = fmaxf(usage[k], EPS);
    const float* row = es + (size_t)k * Dd;
    const int d = lane * 8;
    float4 a = *(const float4*)(row + d);
    float4 c = *(const float4*)(row + d + 4);
    float ef[8] = {a.x/uc, a.y/uc, a.z/uc, a.w/uc, c.x/uc, c.y/uc, c.z/uc, c.w/uc};
    Pack8 ph;
    double e2 = 0.0;
#pragma unroll
    for (int j = 0; j < 8; ++j) {
        ph.h[j] = (__bf16)ef[j];
        e2 = fma((double)ef[j], (double)ef[j], e2);
    }
    size_t base = (size_t)k * Dd + d;
    *(int4*)(Eh + base) = ph.v;
    *(float4*)(embf + base)     = make_float4(ef[0], ef[1], ef[2], ef[3]);
    *(float4*)(embf + base + 4) = make_float4(ef[4], ef[5], ef[6], ef[7]);
#pragma unroll
    for (int off = 32; off >= 1; off >>= 1) e2 += __shfl_down(e2, off, 64);
    if (lane == 0) { e2d[k] = e2; e2f[k] = (float)e2; }
}

// ---------------- main GEMM: 256x256 tile, BK=64, cross-phase pipeline ------
// Round-6 verified kernel (139.5 us, MfmaUtil 44%, conflicts 0), single launch.
__device__ __forceinline__ void stageA2(const ushort* __restrict__ Xh, char* buf,
                                        int m0, int d0, int tid, int j0) {
#pragma unroll
    for (int j = 0; j < 2; ++j) {
        int s = (j0 + j) * 512 + tid;
        int row = s >> 3;
        int clog = (s & 7) ^ (row & 7);            // inverse swizzle on SOURCE
        gld16(Xh + (size_t)(m0 + row) * Dd + d0 + clog * 8, buf + s * 16);
    }
}
__device__ __forceinline__ void stageB2(const ushort* __restrict__ Eh, char* buf,
                                        int n0, int d0, int tid, int j0) {
#pragma unroll
    for (int j = 0; j < 2; ++j) {
        int s = (j0 + j) * 512 + tid;
        int row = s >> 3;
        int clog = (s & 7) ^ (row & 7);
        gld16(Eh + (size_t)(n0 + row) * Dd + d0 + clog * 8, buf + 32768 + s * 16);
    }
}

#define SB() __builtin_amdgcn_sched_barrier(0)

__global__ __launch_bounds__(512) void gemm_kernel(const ushort* __restrict__ Xh,
                                                   const ushort* __restrict__ Eh,
                                                   const float* __restrict__ e2f,
                                                   uint2* __restrict__ colres) {
    __shared__ int4 ldsbuf[8192];   // 128 KiB
    char* lds = (char*)ldsbuf;

    const int tid = threadIdx.x;
    // grid 2048 = 64 mb x 32 nb. XCD chunks of 256, 8mb x 4nb supertiles
    // (2MB X + 1MB E = 3MB, fits per-XCD L2; 32 CUs run one supertile).
    int wg = blockIdx.x;
    int wgid = (wg & 7) * 256 + (wg >> 3);
    int st = wgid >> 5, u = wgid & 31;
    int mb = (st >> 3) * 8 + (u & 7);
    int nb = (st & 7) * 4 + (u >> 3);
    const int m0 = mb * 256, n0 = nb * 256;

    const int wave = tid >> 6, lane = tid & 63;
    const int wm = wave >> 1, wn = wave & 1;
    const int mw = wm * 64, nw = wn * 128;
    const int fm = lane & 15, fq = lane >> 4;
    const int fm7 = fm & 7;
    const int x0 = (fq ^ fm7) * 16;          // kk=0 swizzled chunk byte offset
    const int x1 = ((4 + fq) ^ fm7) * 16;    // kk=1
    const int pao = (mw + fm) * 128;
    const int pbo = 32768 + (nw + fm) * 128;

    f32x4 acc[8][4] = {};
    bf16x8 a0[4], a1[4], bl0[4], bh0[4], bl1[4], bh1[4];

    // prologue: tile0 full + tile1's A1; vmcnt(2) keeps A1(1) in flight
    stageA2(Xh, lds, m0, 0, tid, 0);
    stageA2(Xh, lds, m0, 0, tid, 2);
    stageB2(Eh, lds, n0, 0, tid, 0);
    stageB2(Eh, lds, n0, 0, tid, 2);
    stageA2(Xh, lds + 65536, m0, 64, tid, 0);
    asm volatile("s_waitcnt vmcnt(2)" ::: "memory");
    __builtin_amdgcn_s_barrier();
    SB();
    // S1(0) reads
#pragma unroll
    for (int i = 0; i < 4; ++i) a0[i]  = *(const bf16x8*)(lds + pao + i * 2048 + x0);
#pragma unroll
    for (int i = 0; i < 4; ++i) bl0[i] = *(const bf16x8*)(lds + pbo + i * 2048 + x0);
    SB();

    for (int t = 0; t < 8; ++t) {
        char* bufc = lds + (t & 1) * 65536;
        char* bufn = lds + ((t + 1) & 1) * 65536;
        const char* pA = bufc + pao;
        const char* pB = bufc + pbo;
        const int d1 = (t + 1) * 64, d2 = (t + 2) * 64;

        // ---- P1: issue S2 reads | stage A2(t+1) | MFMA S1 ------------------
#pragma unroll
        for (int i = 0; i < 4; ++i) bh0[i] = *(const bf16x8*)(pB + 8192 + i * 2048 + x0);
        SB();
        if (t + 1 < 8) stageA2(Xh, bufn, m0, d1, tid, 2);
        SB();
        asm volatile("s_waitcnt lgkmcnt(4)" ::: "memory");   // S1 done
        SB();
        __builtin_amdgcn_s_setprio(1);
#pragma unroll
        for (int i = 0; i < 4; ++i)
#pragma unroll
            for (int j = 0; j < 4; ++j)
                acc[i][j] = __builtin_amdgcn_mfma_f32_16x16x32_bf16(bl0[i], a0[j], acc[i][j], 0, 0, 0);
        __builtin_amdgcn_s_setprio(0);
        SB();
        __builtin_amdgcn_s_barrier();

        // ---- P2: issue S3 reads | stage B1(t+1) | MFMA S2 ------------------
#pragma unroll
        for (int i = 0; i < 4; ++i) a1[i]  = *(const bf16x8*)(pA + i * 2048 + x1);
#pragma unroll
        for (int i = 0; i < 4; ++i) bl1[i] = *(const bf16x8*)(pB + i * 2048 + x1);
        SB();
        if (t + 1 < 8) stageB2(Eh, bufn, n0, d1, tid, 0);
        SB();
        asm volatile("s_waitcnt lgkmcnt(8)" ::: "memory");   // S2 done
        SB();
        __builtin_amdgcn_s_setprio(1);
#pragma unroll
        for (int i = 0; i < 4; ++i)
#pragma unroll
            for (int j = 0; j < 4; ++j)
                acc[i + 4][j] = __builtin_amdgcn_mfma_f32_16x16x32_bf16(bh0[i], a0[j], acc[i + 4][j], 0, 0, 0);
        __builtin_amdgcn_s_setprio(0);
        SB();
        __builtin_amdgcn_s_barrier();

        // ---- P3: issue S4 reads | stage B2(t+1) | MFMA S3 ------------------
#pragma unroll
        for (int i = 0; i < 4; ++i) bh1[i] = *(const bf16x8*)(pB + 8192 + i * 2048 + x1);
        SB();
        if (t + 1 < 8) stageB2(Eh, bufn, n0, d1, tid, 2);
        SB();
        asm volatile("s_waitcnt lgkmcnt(4)" ::: "memory");   // S3 done
        SB();
        __builtin_amdgcn_s_setprio(1);
#pragma unroll
        for (int i = 0; i < 4; ++i)
#pragma unroll
            for (int j = 0; j < 4; ++j)
                acc[i][j] = __builtin_amdgcn_mfma_f32_16x16x32_bf16(bl1[i], a1[j], acc[i][j], 0, 0, 0);
        __builtin_amdgcn_s_setprio(0);
        SB();
        __builtin_amdgcn_s_barrier();

        // ---- P4: drain reads | barrier | stage A1(t+2) into bufc | MFMA S4 -
        asm volatile("s_waitcnt lgkmcnt(0)" ::: "memory");   // S4 done
        SB();
        __builtin_amdgcn_s_barrier();   // all waves' bufc reads complete
        if (t + 2 < 8) stageA2(Xh, bufc, m0, d2, tid, 0);
        SB();
        __builtin_amdgcn_s_setprio(1);
#pragma unroll
        for (int i = 0; i < 4; ++i)
#pragma unroll
            for (int j = 0; j < 4; ++j)
                acc[i + 4][j] = __builtin_amdgcn_mfma_f32_16x16x32_bf16(bh1[i], a1[j], acc[i + 4][j], 0, 0, 0);
        __builtin_amdgcn_s_setprio(0);
        SB();

        // ---- boundary: counted vmcnt + barrier + S1(t+1) reads -------------
        if (t < 7) {
            if (t < 6) { asm volatile("s_waitcnt vmcnt(2)" ::: "memory"); }
            else       { asm volatile("s_waitcnt vmcnt(0)" ::: "memory"); }
            SB();
            __builtin_amdgcn_s_barrier();
            SB();
            const char* pAn = bufn + pao;
            const char* pBn = bufn + pbo;
#pragma unroll
            for (int i = 0; i < 4; ++i) a0[i]  = *(const bf16x8*)(pAn + i * 2048 + x0);
#pragma unroll
            for (int i = 0; i < 4; ++i) bl0[i] = *(const bf16x8*)(pBn + i * 2048 + x0);
            SB();
        }
    }

    // ---- epilogue: top-2 per (m-row, 128-n-block), n lane-local ------------
    // acc[ni][mj][r]: n = nw + ni*16 + fq*4 + r ; m = mw + mj*16 + fm
    float4 e2v[8];
#pragma unroll
    for (int ni = 0; ni < 8; ++ni)
        e2v[ni] = *(const float4*)(e2f + n0 + nw + ni * 16 + fq * 4);

    const int cb = (n0 + nw) >> 7;   // 128-col block index (0..63)
#pragma unroll
    for (int mj = 0; mj < 4; ++mj) {
        unsigned s1 = 0xFFFFFFFFu, s2 = 0xFFFFFFFFu;
#pragma unroll
        for (int ni = 0; ni < 8; ++ni) {
            unsigned k0 = (monokey(fmaf(-2.0f, acc[ni][mj][0], e2v[ni].x)) & 0xFFFFFF80u) | (unsigned)(ni * 16 + fq * 4 + 0);
            unsigned k1 = (monokey(fmaf(-2.0f, acc[ni][mj][1], e2v[ni].y)) & 0xFFFFFF80u) | (unsigned)(ni * 16 + fq * 4 + 1);
            unsigned k2 = (monokey(fmaf(-2.0f, acc[ni][mj][2], e2v[ni].z)) & 0xFFFFFF80u) | (unsigned)(ni * 16 + fq * 4 + 2);
            unsigned k3 = (monokey(fmaf(-2.0f, acc[ni][mj][3], e2v[ni].w)) & 0xFFFFFF80u) | (unsigned)(ni * 16 + fq * 4 + 3);
            unsigned lo01 = min(k0, k1), hi01 = max(k0, k1);
            unsigned lo23 = min(k2, k3), hi23 = max(k2, k3);
            unsigned p1 = min(lo01, lo23);
            unsigned p2 = min(max(lo01, lo23), min(hi01, hi23));
            merge2u(s1, s2, p1, p2);
        }
        // reduce across fq groups (lanes fm, fm+16, fm+32, fm+48)
#pragma unroll
        for (int stg = 16; stg <= 32; stg <<= 1) {
            unsigned b1 = __shfl_xor(s1, stg, 64);
            unsigned b2 = __shfl_xor(s2, stg, 64);
            merge2u(s1, s2, b1, b2);
        }
        if (lane < 16)
            colres[(size_t)(m0 + mw + mj * 16 + lane) * 64 + cb] = make_uint2(s1, s2);
    }
}

// ------- merge: global top-4 of block-pairs + collision ballot; tiering -----
__global__ __launch_bounds__(256) void merge_kernel(const uint2* __restrict__ colres,
                                                    float* __restrict__ out,
                                                    int* __restrict__ cnt,
                                                    int* __restrict__ queueC,
                                                    int* __restrict__ queueF) {
    const int wave = threadIdx.x >> 6, lane = threadIdx.x & 63;
    const int row = blockIdx.x * 4 + wave;
    uint2 q = colres[(size_t)row * 64 + lane];
    const unsigned nb128 = (unsigned)(lane * 128);
    u64 a1 = ((u64)(q.x & 0xFFFFFF80u) << 32) | (nb128 + (q.x & 127u));
    u64 a2 = ((u64)(q.y & 0xFFFFFF80u) << 32) | (nb128 + (q.y & 127u));
    u64 a3 = ~0ull, a4 = ~0ull;
#pragma unroll
    for (int st = 1; st < 64; st <<= 1)
        merge4q(a1, a2, a3, a4, shflx64(a1, st), shflx64(a2, st), shflx64(a3, st), shflx64(a4, st));
    // all lanes hold the global top-4 now
    float v1 = unmono((unsigned)(a1 >> 32));
    // block-collision: this lane's block has 2+ entries within TAU of global min
    u64 coll = __ballot(unmono(q.y) < v1 + TAU);
    if (lane == 0) {
        float v2 = unmono((unsigned)(a2 >> 32));
        float v4 = unmono((unsigned)(a4 >> 32));
        int i1 = (int)(unsigned)a1;
        out[row] = (float)i1;
        if (coll != 0ull || (v4 - v1 < TAU)) {   // candidate set may be incomplete
            int p = atomicAdd(&cnt[1], 1);
            queueF[p] = row;
        } else if (v2 - v1 < TAU) {              // winner provably in {i1..i4}
            int p = atomicAdd(&cnt[0], 1);
            queueC[p * 5]     = row;
            queueC[p * 5 + 1] = i1;
            queueC[p * 5 + 2] = (int)(unsigned)a2;
            queueC[p * 5 + 3] = (int)(unsigned)a3;
            queueC[p * 5 + 4] = (int)(unsigned)a4;
        }
    }
}

// ------- candidate rescore: exact fp64 on {i1..i4}, one wave per query ------
__global__ __launch_bounds__(256) void cand_kernel(const float* __restrict__ Xf,
                                                   const float* __restrict__ embf,
                                                   const double* __restrict__ e2d,
                                                   const int* __restrict__ cnt,
                                                   const int* __restrict__ queueC,
                                                   float* __restrict__ out) {
    const int wv = (blockIdx.x << 2) | (threadIdx.x >> 6);
    const int lane = threadIdx.x & 63;
    const int n = cnt[0];
    for (int p = wv; p < n; p += gridDim.x * 4) {
        int row = queueC[p * 5];
        int ci[4] = {queueC[p*5+1], queueC[p*5+2], queueC[p*5+3], queueC[p*5+4]};
        const float* xr = Xf + (size_t)row * Dd + lane * 8;
        float4 xa = *(const float4*)xr;
        float4 xb = *(const float4*)(xr + 4);
        double s[4] = {0.0, 0.0, 0.0, 0.0};
#pragma unroll
        for (int c = 0; c < 4; ++c) {
            const float* er = embf + (size_t)ci[c] * Dd + lane * 8;
            float4 ea = *(const float4*)er;
            float4 eb = *(const float4*)(er + 4);
            double t = 0.0;
            t = fma((double)xa.x, (double)ea.x, t);
            t = fma((double)xa.y, (double)ea.y, t);
            t = fma((double)xa.z, (double)ea.z, t);
            t = fma((double)xa.w, (double)ea.w, t);
            t = fma((double)xb.x, (double)eb.x, t);
            t = fma((double)xb.y, (double)eb.y, t);
            t = fma((double)xb.z, (double)eb.z, t);
            t = fma((double)xb.w, (double)eb.w, t);
            s[c] = t;
        }
#pragma unroll
        for (int off = 32; off >= 1; off >>= 1) {
#pragma unroll
            for (int c = 0; c < 4; ++c) s[c] += __shfl_down(s[c], off, 64);
        }
        if (lane == 0) {
            double bv = DBL_MAX; int bi = 0x7fffffff;
#pragma unroll
            for (int c = 0; c < 4; ++c) {
                double dv = fma(-2.0, s[c], e2d[ci[c]]);
                if (dv < bv || (dv == bv && ci[c] < bi)) { bv = dv; bi = ci[c]; }
            }
            out[row] = (float)bi;
        }
    }
}

// -------- full exact scan v3: 32 chunks x 256 clusters, chunk-major ---------
// Task = (ch, qi), chunk-major (ch = task/nF) so concurrent blocks share the
// same 0.5 MB chunk -> per-XCD L2 absorbs re-reads (L3 traffic ~8x16MB, not
// nF x 16MB). Grid 2048 = 8 blocks/CU = 32 waves/CU (v1 was 1 block/CU,
// latency-starved at 8.6% occupancy). 1 cluster/thread, 512 fp64 FMA each.
__global__ __launch_bounds__(256) void fscan_kernel(const float* __restrict__ Xf,
                                                    const float* __restrict__ embf,
                                                    const double* __restrict__ e2d,
                                                    const int* __restrict__ cnt,
                                                    const int* __restrict__ queueF,
                                                    double* __restrict__ fbv,
                                                    int* __restrict__ fbi) {
    __shared__ float xs[512];
    __shared__ double sv[256];
    __shared__ int si[256];
    const int tid = threadIdx.x;
    const int nF = cnt[1];
    const int ntask = nF * 32;
    for (int task = blockIdx.x; task < ntask; task += gridDim.x) {
        const int ch = task / nF, qi = task - ch * nF;   // chunk-major
        const int row = queueF[qi];
        __syncthreads();
        for (int d = tid; d < Dd; d += 256)
            xs[d] = Xf[(size_t)row * Dd + d];
        __syncthreads();
        const int k = ch * 256 + tid;
        const float* er = embf + (size_t)k * Dd;
        double a0 = 0, a1 = 0, a2 = 0, a3 = 0;
        for (int d = 0; d < Dd; d += 4) {
            float4 e = *(const float4*)(er + d);
            float4 xv = *(const float4*)&xs[d];
            a0 = fma((double)e.x, (double)xv.x, a0);
            a1 = fma((double)e.y, (double)xv.y, a1);
            a2 = fma((double)e.z, (double)xv.z, a2);
            a3 = fma((double)e.w, (double)xv.w, a3);
        }
        double bv = fma(-2.0, (a0 + a1) + (a2 + a3), e2d[k]);
        int bi = k;
        sv[tid] = bv; si[tid] = bi;
        __syncthreads();
        for (int off = 128; off > 0; off >>= 1) {
            if (tid < off) {
                if (sv[tid + off] < sv[tid] ||
                    (sv[tid + off] == sv[tid] && si[tid + off] < si[tid])) {
                    sv[tid] = sv[tid + off]; si[tid] = si[tid + off];
                }
            }
            __syncthreads();
        }
        if (tid == 0) { fbv[(size_t)qi * 32 + ch] = sv[0]; fbi[(size_t)qi * 32 + ch] = si[0]; }
    }
}

__global__ void fmerge_kernel(const int* __restrict__ cnt,
                              const int* __restrict__ queueF,
                              const double* __restrict__ fbv,
                              const int* __restrict__ fbi,
                              float* __restrict__ out) {
    const int nF = cnt[1];
    for (int qi = blockIdx.x * 256 + threadIdx.x; qi < nF; qi += gridDim.x * 256) {
        double bv = DBL_MAX; int bi = 0x7fffffff;
        for (int c = 0; c < 32; ++c) {
            double v = fbv[(size_t)qi * 32 + c]; int i = fbi[(size_t)qi * 32 + c];
            if (v < bv || (v == bv && i < bi)) { bv = v; bi = i; }
        }
        out[queueF[qi]] = (float)bi;
    }
}

// ---------------- gather quantized rows, coalesced along t ------------------
__global__ __launch_bounds__(256) void gather_kernel(const float* __restrict__ embf,
                                                     float* __restrict__ out) {
    __shared__ int cs[64];
    const int tid = threadIdx.x;
    const int m0 = blockIdx.x * 64;
    const int b = m0 >> 10;
    const int t0 = m0 & (Tt - 1);
    if (tid < 64) cs[tid] = (int)out[m0 + tid];
    __syncthreads();
    const int tq = tid & 63;
    const int dg = tid >> 6;
    const int c = cs[tq];
    const float* row = embf + (size_t)c * Dd;   // embf == exact fp32 es/clip(u)
    float* ob = out + Nq + (size_t)b * Dd * Tt + t0 + tq;
#pragma unroll 4
    for (int d = dg * 128; d < dg * 128 + 128; ++d)
        ob[(size_t)d * Tt] = row[d];
}

extern "C" void kernel_launch(void* const* d_in, const int* in_sizes, int n_in,
                              void* d_out, int out_size, void* d_ws, size_t ws_size,
                              hipStream_t stream) {
    const float* x     = (const float*)d_in[0];
    const float* es    = (const float*)d_in[1];
    const float* usage = (const float*)d_in[2];
    float* out = (float*)d_out;

    char* w = (char*)d_ws;
    ushort* Xh = (ushort*)w;   w += (size_t)Nq * Dd * 2;      // 16 MB
    ushort* Eh = (ushort*)w;   w += (size_t)Kk * Dd * 2;      //  8 MB
    float*  Xf = (float*)w;    w += (size_t)Nq * Dd * 4;      // 32 MB
    float*  embf = (float*)w;  w += (size_t)Kk * Dd * 4;      // 16 MB
    double* e2d = (double*)w;  w += (size_t)Kk * 8;
    float*  e2f = (float*)w;   w += (size_t)Kk * 4;
    uint2* colres = (uint2*)w; w += (size_t)Nq * 64 * 8;      // 8.4 MB
    int* cnt = (int*)w;        w += 256;
    int* queueC = (int*)w;     w += (size_t)Nq * 5 * 4;
    int* queueF = (int*)w;     w += (size_t)Nq * 4;
    // fbv/fbi alias Xh (dead after gemm_kernel; fscan runs strictly later)
    // fbv: worst-case Nq*32*8 = 4 MB at +0; fbi: Nq*32*4 = 2 MB at +8 MB.
    double* fbv = (double*)Xh;
    int*    fbi = (int*)((char*)Xh + 8 * 1024 * 1024);

    split_x_kernel<<<2048, 256, 0, stream>>>(x, Xh, Xf, cnt);
    split_e_kernel<<<Kk / 4, 256, 0, stream>>>(es, usage, Eh, embf, e2d, e2f);
    gemm_kernel<<<2048, 512, 0, stream>>>(Xh, Eh, e2f, colres);
    merge_kernel<<<Nq / 4, 256, 0, stream>>>(colres, out, cnt, queueC, queueF);
    cand_kernel<<<256, 256, 0, stream>>>(Xf, embf, e2d, cnt, queueC, out);
    fscan_kernel<<<2048, 256, 0, stream>>>(Xf, embf, e2d, cnt, queueF, fbv, fbi);
    fmerge_kernel<<<64, 256, 0, stream>>>(cnt, queueF, fbv, fbi, out);
    gather_kernel<<<Nq / 64, 256, 0, stream>>>(embf, out);
}

// Round 12
// 350.943 us; speedup vs baseline: 1.0885x; 1.0158x over previous
//
#include <hip/hip_runtime.h>
#include <hip/hip_bf16.h>
#include <cfloat>
#include <stdint.h>

#define EPS 1e-5f
constexpr int Dd = 512, Tt = 1024, Kk = 8192;
constexpr int Nq = 16 * 1024;
constexpr float TAU = 1.5f;   // ~7 sigma of 1-product bf16 error + key quant

typedef __bf16 bf16x8 __attribute__((ext_vector_type(8)));
typedef float  f32x4  __attribute__((ext_vector_type(4)));
typedef unsigned long long u64;

union Pack8 { __bf16 h[8]; int4 v; };

__device__ __forceinline__ void gld16(const void* g, void* l) {
    __builtin_amdgcn_global_load_lds(
        (const __attribute__((address_space(1))) uint32_t*)g,
        (__attribute__((address_space(3))) uint32_t*)l, 16, 0, 0);
}

// ---- monotone fp32 -> u32 key helpers --------------------------------------
__device__ __forceinline__ unsigned monokey(float s) {
    unsigned b = __float_as_uint(s);
    return b ^ ((unsigned)((int)b >> 31) | 0x80000000u);
}
__device__ __forceinline__ float unmono(unsigned u) {
    u = (u & 0x80000000u) ? (u ^ 0x80000000u) : ~u;
    return __uint_as_float(u);
}

// ---- sorted-pair / sorted-quad merges --------------------------------------
__device__ __forceinline__ void merge2u(unsigned& a1, unsigned& a2, unsigned b1, unsigned b2) {
    unsigned c1 = min(a1, b1);
    unsigned c2 = min(max(a1, b1), min(a2, b2));
    a1 = c1; a2 = c2;
}
__device__ __forceinline__ u64 umin64(u64 a, u64 b) { return a < b ? a : b; }
__device__ __forceinline__ u64 umax64(u64 a, u64 b) { return a > b ? a : b; }
__device__ __forceinline__ void merge4q(u64& a1, u64& a2, u64& a3, u64& a4,
                                        u64 b1, u64 b2, u64 b3, u64 b4) {
    u64 c1 = umin64(a1, b1);
    u64 c2 = umin64(umin64(a2, b2), umax64(a1, b1));
    u64 c3 = umin64(umin64(a3, b3), umin64(umax64(a2, b1), umax64(a1, b2)));
    u64 c4 = umin64(umin64(a4, b4), umin64(umax64(a3, b1), umax64(a1, b3)));
    c4 = umin64(c4, umax64(a2, b2));
    a1 = c1; a2 = c2; a3 = c3; a4 = c4;
}
__device__ __forceinline__ u64 shflx64(u64 v, int m) {
    int lo = __shfl_xor((int)(unsigned)v, m, 64);
    int hi = __shfl_xor((int)(v >> 32), m, 64);
    return ((u64)(unsigned)hi << 32) | (unsigned)lo;
}

// ---------------- P1: x (B,D,T) -> Xh bf16 + Xf fp32, both (B*T, D) ---------
__global__ __launch_bounds__(256) void split_x_kernel(const float* __restrict__ x,
                                                      ushort* __restrict__ Xh,
                                                      float* __restrict__ Xf,
                                                      int* __restrict__ cnt) {
    if (blockIdx.x == 0 && threadIdx.x < 2) cnt[threadIdx.x] = 0;
    __shared__ float Ls[64][68];
    const int tid = threadIdx.x, bid = blockIdx.x;
    const int b  = bid >> 7;
    const int d0 = ((bid >> 4) & 7) * 64;
    const int t0 = (bid & 15) * 64;
    const float* xb = x + ((size_t)b * Dd + d0) * Tt + t0;
#pragma unroll
    for (int it = 0; it < 4; ++it) {
        int s = it * 256 + tid;
        int d = s >> 4, c = (s & 15) * 4;
        float4 g = *(const float4*)(xb + (size_t)d * Tt + c);
        *(float4*)&Ls[d][c] = g;
    }
    __syncthreads();
    const int t = tid >> 2;
    const int dseg = (tid & 3) * 16;
    Pack8 ph[2];
    float vf[16];
#pragma unroll
    for (int dd = 0; dd < 16; ++dd) {
        float v = Ls[dseg + dd][t];
        vf[dd] = v;
        ph[dd >> 3].h[dd & 7] = (__bf16)v;
    }
    size_t base = ((size_t)(b * Tt + t0 + t)) * Dd + d0 + dseg;
    *(int4*)(Xh + base)     = ph[0].v;
    *(int4*)(Xh + base + 8) = ph[1].v;
#pragma unroll
    for (int g = 0; g < 4; ++g)
        *(float4*)(Xf + base + g * 4) = make_float4(vf[g*4], vf[g*4+1], vf[g*4+2], vf[g*4+3]);
}

// ---------------- P2: emb=es/clip(u) -> Eh bf16 + embf fp32 + e2 ------------
__global__ __launch_bounds__(256) void split_e_kernel(const float* __restrict__ es,
                                                      const float* __restrict__ usage,
                                                      ushort* __restrict__ Eh,
                                                      float* __restrict__ embf,
                                                      double* __restrict__ e2d,
                                                      float* __restrict__ e2f) {
    const int wave = threadIdx.x >> 6, lane = threadIdx.x & 63;
    const int k = blockIdx.x * 4 + wave;
    const float uc = fmaxf(usage[k], EPS);
    const float* row = es + (size_t)k * Dd;
    const int d = lane * 8;
    float4 a = *(const float4*)(row + d);
    float4 c = *(const float4*)(row + d + 4);
    float ef[8] = {a.x/uc, a.y/uc, a.z/uc, a.w/uc, c.x/uc, c.y/uc, c.z/uc, c.w/uc};
    Pack8 ph;
    double e2 = 0.0;
#pragma unroll
    for (int j = 0; j < 8; ++j) {
        ph.h[j] = (__bf16)ef[j];
        e2 = fma((double)ef[j], (double)ef[j], e2);
    }
    size_t base = (size_t)k * Dd + d;
    *(int4*)(Eh + base) = ph.v;
    *(float4*)(embf + base)     = make_float4(ef[0], ef[1], ef[2], ef[3]);
    *(float4*)(embf + base + 4) = make_float4(ef[4], ef[5], ef[6], ef[7]);
#pragma unroll
    for (int off = 32; off >= 1; off >>= 1) e2 += __shfl_down(e2, off, 64);
    if (lane == 0) { e2d[k] = e2; e2f[k] = (float)e2; }
}

// ---------------- main GEMM: 256x256 tile, BK=64, cross-phase pipeline ------
// Round-6 verified K-loop. Diagnostic 4-way split: wgbase selects the
// supertile quarter; per launch 512 blocks = 8 XCD chunks of 64.
__device__ __forceinline__ void stageA2(const ushort* __restrict__ Xh, char* buf,
                                        int m0, int d0, int tid, int j0) {
#pragma unroll
    for (int j = 0; j < 2; ++j) {
        int s = (j0 + j) * 512 + tid;
        int row = s >> 3;
        int clog = (s & 7) ^ (row & 7);            // inverse swizzle on SOURCE
        gld16(Xh + (size_t)(m0 + row) * Dd + d0 + clog * 8, buf + s * 16);
    }
}
__device__ __forceinline__ void stageB2(const ushort* __restrict__ Eh, char* buf,
                                        int n0, int d0, int tid, int j0) {
#pragma unroll
    for (int j = 0; j < 2; ++j) {
        int s = (j0 + j) * 512 + tid;
        int row = s >> 3;
        int clog = (s & 7) ^ (row & 7);
        gld16(Eh + (size_t)(n0 + row) * Dd + d0 + clog * 8, buf + 32768 + s * 16);
    }
}

#define SB() __builtin_amdgcn_sched_barrier(0)

__global__ __launch_bounds__(512) void gemm_kernel(const ushort* __restrict__ Xh,
                                                   const ushort* __restrict__ Eh,
                                                   const float* __restrict__ e2f,
                                                   uint2* __restrict__ colres,
                                                   int wgbase) {
    __shared__ int4 ldsbuf[8192];   // 128 KiB
    char* lds = (char*)ldsbuf;

    const int tid = threadIdx.x;
    int wg = blockIdx.x;
    int wgid = wgbase + (wg & 7) * 64 + (wg >> 3);
    int st = wgid >> 5, u = wgid & 31;
    int mb = (st >> 3) * 8 + (u & 7);
    int nb = (st & 7) * 4 + (u >> 3);
    const int m0 = mb * 256, n0 = nb * 256;

    const int wave = tid >> 6, lane = tid & 63;
    const int wm = wave >> 1, wn = wave & 1;
    const int mw = wm * 64, nw = wn * 128;
    const int fm = lane & 15, fq = lane >> 4;
    const int fm7 = fm & 7;
    const int x0 = (fq ^ fm7) * 16;          // kk=0 swizzled chunk byte offset
    const int x1 = ((4 + fq) ^ fm7) * 16;    // kk=1
    const int pao = (mw + fm) * 128;
    const int pbo = 32768 + (nw + fm) * 128;

    f32x4 acc[8][4] = {};
    bf16x8 a0[4], a1[4], bl0[4], bh0[4], bl1[4], bh1[4];

    // prologue: tile0 full + tile1's A1; vmcnt(2) keeps A1(1) in flight
    stageA2(Xh, lds, m0, 0, tid, 0);
    stageA2(Xh, lds, m0, 0, tid, 2);
    stageB2(Eh, lds, n0, 0, tid, 0);
    stageB2(Eh, lds, n0, 0, tid, 2);
    stageA2(Xh, lds + 65536, m0, 64, tid, 0);
    asm volatile("s_waitcnt vmcnt(2)" ::: "memory");
    __builtin_amdgcn_s_barrier();
    SB();
    // S1(0) reads
#pragma unroll
    for (int i = 0; i < 4; ++i) a0[i]  = *(const bf16x8*)(lds + pao + i * 2048 + x0);
#pragma unroll
    for (int i = 0; i < 4; ++i) bl0[i] = *(const bf16x8*)(lds + pbo + i * 2048 + x0);
    SB();

    for (int t = 0; t < 8; ++t) {
        char* bufc = lds + (t & 1) * 65536;
        char* bufn = lds + ((t + 1) & 1) * 65536;
        const char* pA = bufc + pao;
        const char* pB = bufc + pbo;
        const int d1 = (t + 1) * 64, d2 = (t + 2) * 64;

        // ---- P1: issue S2 reads | stage A2(t+1) | MFMA S1 ------------------
#pragma unroll
        for (int i = 0; i < 4; ++i) bh0[i] = *(const bf16x8*)(pB + 8192 + i * 2048 + x0);
        SB();
        if (t + 1 < 8) stageA2(Xh, bufn, m0, d1, tid, 2);
        SB();
        asm volatile("s_waitcnt lgkmcnt(4)" ::: "memory");   // S1 done
        SB();
        __builtin_amdgcn_s_setprio(1);
#pragma unroll
        for (int i = 0; i < 4; ++i)
#pragma unroll
            for (int j = 0; j < 4; ++j)
                acc[i][j] = __builtin_amdgcn_mfma_f32_16x16x32_bf16(bl0[i], a0[j], acc[i][j], 0, 0, 0);
        __builtin_amdgcn_s_setprio(0);
        SB();
        __builtin_amdgcn_s_barrier();

        // ---- P2: issue S3 reads | stage B1(t+1) | MFMA S2 ------------------
#pragma unroll
        for (int i = 0; i < 4; ++i) a1[i]  = *(const bf16x8*)(pA + i * 2048 + x1);
#pragma unroll
        for (int i = 0; i < 4; ++i) bl1[i] = *(const bf16x8*)(pB + i * 2048 + x1);
        SB();
        if (t + 1 < 8) stageB2(Eh, bufn, n0, d1, tid, 0);
        SB();
        asm volatile("s_waitcnt lgkmcnt(8)" ::: "memory");   // S2 done
        SB();
        __builtin_amdgcn_s_setprio(1);
#pragma unroll
        for (int i = 0; i < 4; ++i)
#pragma unroll
            for (int j = 0; j < 4; ++j)
                acc[i + 4][j] = __builtin_amdgcn_mfma_f32_16x16x32_bf16(bh0[i], a0[j], acc[i + 4][j], 0, 0, 0);
        __builtin_amdgcn_s_setprio(0);
        SB();
        __builtin_amdgcn_s_barrier();

        // ---- P3: issue S4 reads | stage B2(t+1) | MFMA S3 ------------------
#pragma unroll
        for (int i = 0; i < 4; ++i) bh1[i] = *(const bf16x8*)(pB + 8192 + i * 2048 + x1);
        SB();
        if (t + 1 < 8) stageB2(Eh, bufn, n0, d1, tid, 2);
        SB();
        asm volatile("s_waitcnt lgkmcnt(4)" ::: "memory");   // S3 done
        SB();
        __builtin_amdgcn_s_setprio(1);
#pragma unroll
        for (int i = 0; i < 4; ++i)
#pragma unroll
            for (int j = 0; j < 4; ++j)
                acc[i][j] = __builtin_amdgcn_mfma_f32_16x16x32_bf16(bl1[i], a1[j], acc[i][j], 0, 0, 0);
        __builtin_amdgcn_s_setprio(0);
        SB();
        __builtin_amdgcn_s_barrier();

        // ---- P4: drain reads | barrier | stage A1(t+2) into bufc | MFMA S4 -
        asm volatile("s_waitcnt lgkmcnt(0)" ::: "memory");   // S4 done
        SB();
        __builtin_amdgcn_s_barrier();   // all waves' bufc reads complete
        if (t + 2 < 8) stageA2(Xh, bufc, m0, d2, tid, 0);
        SB();
        __builtin_amdgcn_s_setprio(1);
#pragma unroll
        for (int i = 0; i < 4; ++i)
#pragma unroll
            for (int j = 0; j < 4; ++j)
                acc[i + 4][j] = __builtin_amdgcn_mfma_f32_16x16x32_bf16(bh1[i], a1[j], acc[i + 4][j], 0, 0, 0);
        __builtin_amdgcn_s_setprio(0);
        SB();

        // ---- boundary: counted vmcnt + barrier + S1(t+1) reads -------------
        if (t < 7) {
            if (t < 6) { asm volatile("s_waitcnt vmcnt(2)" ::: "memory"); }
            else       { asm volatile("s_waitcnt vmcnt(0)" ::: "memory"); }
            SB();
            __builtin_amdgcn_s_barrier();
            SB();
            const char* pAn = bufn + pao;
            const char* pBn = bufn + pbo;
#pragma unroll
            for (int i = 0; i < 4; ++i) a0[i]  = *(const bf16x8*)(pAn + i * 2048 + x0);
#pragma unroll
            for (int i = 0; i < 4; ++i) bl0[i] = *(const bf16x8*)(pBn + i * 2048 + x0);
            SB();
        }
    }

    // ---- epilogue: top-2 per (m-row, 128-n-block), n lane-local ------------
    float4 e2v[8];
#pragma unroll
    for (int ni = 0; ni < 8; ++ni)
        e2v[ni] = *(const float4*)(e2f + n0 + nw + ni * 16 + fq * 4);

    const int cb = (n0 + nw) >> 7;   // 128-col block index (0..63)
#pragma unroll
    for (int mj = 0; mj < 4; ++mj) {
        unsigned s1 = 0xFFFFFFFFu, s2 = 0xFFFFFFFFu;
#pragma unroll
        for (int ni = 0; ni < 8; ++ni) {
            unsigned k0 = (monokey(fmaf(-2.0f, acc[ni][mj][0], e2v[ni].x)) & 0xFFFFFF80u) | (unsigned)(ni * 16 + fq * 4 + 0);
            unsigned k1 = (monokey(fmaf(-2.0f, acc[ni][mj][1], e2v[ni].y)) & 0xFFFFFF80u) | (unsigned)(ni * 16 + fq * 4 + 1);
            unsigned k2 = (monokey(fmaf(-2.0f, acc[ni][mj][2], e2v[ni].z)) & 0xFFFFFF80u) | (unsigned)(ni * 16 + fq * 4 + 2);
            unsigned k3 = (monokey(fmaf(-2.0f, acc[ni][mj][3], e2v[ni].w)) & 0xFFFFFF80u) | (unsigned)(ni * 16 + fq * 4 + 3);
            unsigned lo01 = min(k0, k1), hi01 = max(k0, k1);
            unsigned lo23 = min(k2, k3), hi23 = max(k2, k3);
            unsigned p1 = min(lo01, lo23);
            unsigned p2 = min(max(lo01, lo23), min(hi01, hi23));
            merge2u(s1, s2, p1, p2);
        }
#pragma unroll
        for (int stg = 16; stg <= 32; stg <<= 1) {
            unsigned b1 = __shfl_xor(s1, stg, 64);
            unsigned b2 = __shfl_xor(s2, stg, 64);
            merge2u(s1, s2, b1, b2);
        }
        if (lane < 16)
            colres[(size_t)(m0 + mw + mj * 16 + lane) * 64 + cb] = make_uint2(s1, s2);
    }
}

// ------- merge: global top-4 of block-pairs + collision ballot; tiering -----
__global__ __launch_bounds__(256) void merge_kernel(const uint2* __restrict__ colres,
                                                    float* __restrict__ out,
                                                    int* __restrict__ cnt,
                                                    int* __restrict__ queueC,
                                                    int* __restrict__ queueF) {
    const int wave = threadIdx.x >> 6, lane = threadIdx.x & 63;
    const int row = blockIdx.x * 4 + wave;
    uint2 q = colres[(size_t)row * 64 + lane];
    const unsigned nb128 = (unsigned)(lane * 128);
    u64 a1 = ((u64)(q.x & 0xFFFFFF80u) << 32) | (nb128 + (q.x & 127u));
    u64 a2 = ((u64)(q.y & 0xFFFFFF80u) << 32) | (nb128 + (q.y & 127u));
    u64 a3 = ~0ull, a4 = ~0ull;
#pragma unroll
    for (int st = 1; st < 64; st <<= 1)
        merge4q(a1, a2, a3, a4, shflx64(a1, st), shflx64(a2, st), shflx64(a3, st), shflx64(a4, st));
    // all lanes hold the global top-4 now
    float v1 = unmono((unsigned)(a1 >> 32));
    u64 coll = __ballot(unmono(q.y) < v1 + TAU);
    if (lane == 0) {
        float v2 = unmono((unsigned)(a2 >> 32));
        float v4 = unmono((unsigned)(a4 >> 32));
        int i1 = (int)(unsigned)a1;
        out[row] = (float)i1;
        if (coll != 0ull || (v4 - v1 < TAU)) {   // candidate set may be incomplete
            int p = atomicAdd(&cnt[1], 1);
            queueF[p] = row;
        } else if (v2 - v1 < TAU) {              // winner provably in {i1..i4}
            int p = atomicAdd(&cnt[0], 1);
            queueC[p * 5]     = row;
            queueC[p * 5 + 1] = i1;
            queueC[p * 5 + 2] = (int)(unsigned)a2;
            queueC[p * 5 + 3] = (int)(unsigned)a3;
            queueC[p * 5 + 4] = (int)(unsigned)a4;
        }
    }
}

// ------- candidate rescore: exact fp64 on {i1..i4}, one wave per query ------
__global__ __launch_bounds__(256) void cand_kernel(const float* __restrict__ Xf,
                                                   const float* __restrict__ embf,
                                                   const double* __restrict__ e2d,
                                                   const int* __restrict__ cnt,
                                                   const int* __restrict__ queueC,
                                                   float* __restrict__ out) {
    const int wv = (blockIdx.x << 2) | (threadIdx.x >> 6);
    const int lane = threadIdx.x & 63;
    const int n = cnt[0];
    for (int p = wv; p < n; p += gridDim.x * 4) {
        int row = queueC[p * 5];
        int ci[4] = {queueC[p*5+1], queueC[p*5+2], queueC[p*5+3], queueC[p*5+4]};
        const float* xr = Xf + (size_t)row * Dd + lane * 8;
        float4 xa = *(const float4*)xr;
        float4 xb = *(const float4*)(xr + 4);
        double s[4] = {0.0, 0.0, 0.0, 0.0};
#pragma unroll
        for (int c = 0; c < 4; ++c) {
            const float* er = embf + (size_t)ci[c] * Dd + lane * 8;
            float4 ea = *(const float4*)er;
            float4 eb = *(const float4*)(er + 4);
            double t = 0.0;
            t = fma((double)xa.x, (double)ea.x, t);
            t = fma((double)xa.y, (double)ea.y, t);
            t = fma((double)xa.z, (double)ea.z, t);
            t = fma((double)xa.w, (double)ea.w, t);
            t = fma((double)xb.x, (double)eb.x, t);
            t = fma((double)xb.y, (double)eb.y, t);
            t = fma((double)xb.z, (double)eb.z, t);
            t = fma((double)xb.w, (double)eb.w, t);
            s[c] = t;
        }
#pragma unroll
        for (int off = 32; off >= 1; off >>= 1) {
#pragma unroll
            for (int c = 0; c < 4; ++c) s[c] += __shfl_down(s[c], off, 64);
        }
        if (lane == 0) {
            double bv = DBL_MAX; int bi = 0x7fffffff;
#pragma unroll
            for (int c = 0; c < 4; ++c) {
                double dv = fma(-2.0, s[c], e2d[ci[c]]);
                if (dv < bv || (dv == bv && ci[c] < bi)) { bv = dv; bi = ci[c]; }
            }
            out[row] = (float)bi;
        }
    }
}

// -------- full exact scan v3: 32 chunks x 256 clusters, chunk-major ---------
// (verified round 11)
__global__ __launch_bounds__(256) void fscan_kernel(const float* __restrict__ Xf,
                                                    const float* __restrict__ embf,
                                                    const double* __restrict__ e2d,
                                                    const int* __restrict__ cnt,
                                                    const int* __restrict__ queueF,
                                                    double* __restrict__ fbv,
                                                    int* __restrict__ fbi) {
    __shared__ float xs[512];
    __shared__ double sv[256];
    __shared__ int si[256];
    const int tid = threadIdx.x;
    const int nF = cnt[1];
    const int ntask = nF * 32;
    for (int task = blockIdx.x; task < ntask; task += gridDim.x) {
        const int ch = task / nF, qi = task - ch * nF;   // chunk-major
        const int row = queueF[qi];
        __syncthreads();
        for (int d = tid; d < Dd; d += 256)
            xs[d] = Xf[(size_t)row * Dd + d];
        __syncthreads();
        const int k = ch * 256 + tid;
        const float* er = embf + (size_t)k * Dd;
        double a0 = 0, a1 = 0, a2 = 0, a3 = 0;
        for (int d = 0; d < Dd; d += 4) {
            float4 e = *(const float4*)(er + d);
            float4 xv = *(const float4*)&xs[d];
            a0 = fma((double)e.x, (double)xv.x, a0);
            a1 = fma((double)e.y, (double)xv.y, a1);
            a2 = fma((double)e.z, (double)xv.z, a2);
            a3 = fma((double)e.w, (double)xv.w, a3);
        }
        double bv = fma(-2.0, (a0 + a1) + (a2 + a3), e2d[k]);
        int bi = k;
        sv[tid] = bv; si[tid] = bi;
        __syncthreads();
        for (int off = 128; off > 0; off >>= 1) {
            if (tid < off) {
                if (sv[tid + off] < sv[tid] ||
                    (sv[tid + off] == sv[tid] && si[tid + off] < si[tid])) {
                    sv[tid] = sv[tid + off]; si[tid] = si[tid + off];
                }
            }
            __syncthreads();
        }
        if (tid == 0) { fbv[(size_t)qi * 32 + ch] = sv[0]; fbi[(size_t)qi * 32 + ch] = si[0]; }
    }
}

__global__ void fmerge_kernel(const int* __restrict__ cnt,
                              const int* __restrict__ queueF,
                              const double* __restrict__ fbv,
                              const int* __restrict__ fbi,
                              float* __restrict__ out) {
    const int nF = cnt[1];
    for (int qi = blockIdx.x * 256 + threadIdx.x; qi < nF; qi += gridDim.x * 256) {
        double bv = DBL_MAX; int bi = 0x7fffffff;
        for (int c = 0; c < 32; ++c) {
            double v = fbv[(size_t)qi * 32 + c]; int i = fbi[(size_t)qi * 32 + c];
            if (v < bv || (v == bv && i < bi)) { bv = v; bi = i; }
        }
        out[queueF[qi]] = (float)bi;
    }
}

// ------- gather v2: LDS-staged rows (coalesced reads), coalesced-t writes ---
// v1 read row[d] with a DIFFERENT row per lane: 64 cache lines per wave-load,
// 16x L2/L3 amplification (~537 MB for 32 MB payload). v2 stages the block's
// 64 rows into LDS via contiguous float4 reads (1x traffic), then the
// transpose read comes from LDS (row stride 516 floats: 16B-aligned, 8-way
// read conflict ~3us/block -- cheap vs the global gather).
__global__ __launch_bounds__(256) void gather_kernel(const float* __restrict__ embf,
                                                     float* __restrict__ out) {
    __shared__ int cs[64];
    __shared__ float Ls[64][516];   // 132 KB
    const int tid = threadIdx.x;
    const int m0 = blockIdx.x * 64;
    const int b = m0 >> 10;
    const int t0 = m0 & (Tt - 1);
    if (tid < 64) cs[tid] = (int)out[m0 + tid];
    __syncthreads();
#pragma unroll
    for (int it = 0; it < 32; ++it) {
        int s = it * 256 + tid;          // 0..8191
        int r = s >> 7, f = (s & 127) * 4;
        *(float4*)&Ls[r][f] = *(const float4*)(embf + (size_t)cs[r] * Dd + f);
    }
    __syncthreads();
    const int tq = tid & 63;
    const int dg = tid >> 6;
    float* ob = out + Nq + (size_t)b * Dd * Tt + t0 + tq;
#pragma unroll 4
    for (int d = dg * 128; d < dg * 128 + 128; ++d)
        ob[(size_t)d * Tt] = Ls[tq][d];
}

extern "C" void kernel_launch(void* const* d_in, const int* in_sizes, int n_in,
                              void* d_out, int out_size, void* d_ws, size_t ws_size,
                              hipStream_t stream) {
    const float* x     = (const float*)d_in[0];
    const float* es    = (const float*)d_in[1];
    const float* usage = (const float*)d_in[2];
    float* out = (float*)d_out;

    char* w = (char*)d_ws;
    ushort* Xh = (ushort*)w;   w += (size_t)Nq * Dd * 2;      // 16 MB
    ushort* Eh = (ushort*)w;   w += (size_t)Kk * Dd * 2;      //  8 MB
    float*  Xf = (float*)w;    w += (size_t)Nq * Dd * 4;      // 32 MB
    float*  embf = (float*)w;  w += (size_t)Kk * Dd * 4;      // 16 MB
    double* e2d = (double*)w;  w += (size_t)Kk * 8;
    float*  e2f = (float*)w;   w += (size_t)Kk * 4;
    uint2* colres = (uint2*)w; w += (size_t)Nq * 64 * 8;      // 8.4 MB
    int* cnt = (int*)w;        w += 256;
    int* queueC = (int*)w;     w += (size_t)Nq * 5 * 4;
    int* queueF = (int*)w;     w += (size_t)Nq * 4;
    // fbv/fbi alias Xh (dead after gemm_kernel; fscan runs strictly later)
    double* fbv = (double*)Xh;
    int*    fbi = (int*)((char*)Xh + 8 * 1024 * 1024);

    split_x_kernel<<<2048, 256, 0, stream>>>(x, Xh, Xf, cnt);
    split_e_kernel<<<Kk / 4, 256, 0, stream>>>(es, usage, Eh, embf, e2d, e2f);
    gemm_kernel<<<512, 512, 0, stream>>>(Xh, Eh, e2f, colres, 0);
    gemm_kernel<<<512, 512, 0, stream>>>(Xh, Eh, e2f, colres, 512);
    gemm_kernel<<<512, 512, 0, stream>>>(Xh, Eh, e2f, colres, 1024);
    gemm_kernel<<<512, 512, 0, stream>>>(Xh, Eh, e2f, colres, 1536);
    merge_kernel<<<Nq / 4, 256, 0, stream>>>(colres, out, cnt, queueC, queueF);
    cand_kernel<<<256, 256, 0, stream>>>(Xf, embf, e2d, cnt, queueC, out);
    fscan_kernel<<<2048, 256, 0, stream>>>(Xf, embf, e2d, cnt, queueF, fbv, fbi);
    fmerge_kernel<<<64, 256, 0, stream>>>(cnt, queueF, fbv, fbi, out);
    gather_kernel<<<Nq / 64, 256, 0, stream>>>(embf, out);
}

// Round 13
// 336.112 us; speedup vs baseline: 1.1365x; 1.0441x over previous
//
#include <hip/hip_runtime.h>
#include <hip/hip_bf16.h>
#include <cfloat>
#include <stdint.h>

#define EPS 1e-5f
constexpr int Dd = 512, Tt = 1024, Kk = 8192;
constexpr int Nq = 16 * 1024;
constexpr float TAU = 1.5f;   // ~7 sigma of 1-product bf16 error + key quant

typedef __bf16 bf16x8 __attribute__((ext_vector_type(8)));
typedef float  f32x4  __attribute__((ext_vector_type(4)));
typedef unsigned long long u64;

union Pack8 { __bf16 h[8]; int4 v; };

__device__ __forceinline__ void gld16(const void* g, void* l) {
    __builtin_amdgcn_global_load_lds(
        (const __attribute__((address_space(1))) uint32_t*)g,
        (__attribute__((address_space(3))) uint32_t*)l, 16, 0, 0);
}

// ---- monotone fp32 -> u32 key helpers --------------------------------------
__device__ __forceinline__ unsigned monokey(float s) {
    unsigned b = __float_as_uint(s);
    return b ^ ((unsigned)((int)b >> 31) | 0x80000000u);
}
__device__ __forceinline__ float unmono(unsigned u) {
    u = (u & 0x80000000u) ? (u ^ 0x80000000u) : ~u;
    return __uint_as_float(u);
}

// ---- sorted-pair / sorted-quad merges --------------------------------------
__device__ __forceinline__ void merge2u(unsigned& a1, unsigned& a2, unsigned b1, unsigned b2) {
    unsigned c1 = min(a1, b1);
    unsigned c2 = min(max(a1, b1), min(a2, b2));
    a1 = c1; a2 = c2;
}
__device__ __forceinline__ u64 umin64(u64 a, u64 b) { return a < b ? a : b; }
__device__ __forceinline__ u64 umax64(u64 a, u64 b) { return a > b ? a : b; }
__device__ __forceinline__ void merge4q(u64& a1, u64& a2, u64& a3, u64& a4,
                                        u64 b1, u64 b2, u64 b3, u64 b4) {
    u64 c1 = umin64(a1, b1);
    u64 c2 = umin64(umin64(a2, b2), umax64(a1, b1));
    u64 c3 = umin64(umin64(a3, b3), umin64(umax64(a2, b1), umax64(a1, b2)));
    u64 c4 = umin64(umin64(a4, b4), umin64(umax64(a3, b1), umax64(a1, b3)));
    c4 = umin64(c4, umax64(a2, b2));
    a1 = c1; a2 = c2; a3 = c3; a4 = c4;
}
__device__ __forceinline__ u64 shflx64(u64 v, int m) {
    int lo = __shfl_xor((int)(unsigned)v, m, 64);
    int hi = __shfl_xor((int)(v >> 32), m, 64);
    return ((u64)(unsigned)hi << 32) | (unsigned)lo;
}

// ---------------- P1: x (B,D,T) -> Xh bf16 + Xf fp32, both (B*T, D) ---------
__global__ __launch_bounds__(256) void split_x_kernel(const float* __restrict__ x,
                                                      ushort* __restrict__ Xh,
                                                      float* __restrict__ Xf,
                                                      int* __restrict__ cnt) {
    if (blockIdx.x == 0 && threadIdx.x < 2) cnt[threadIdx.x] = 0;
    __shared__ float Ls[64][68];
    const int tid = threadIdx.x, bid = blockIdx.x;
    const int b  = bid >> 7;
    const int d0 = ((bid >> 4) & 7) * 64;
    const int t0 = (bid & 15) * 64;
    const float* xb = x + ((size_t)b * Dd + d0) * Tt + t0;
#pragma unroll
    for (int it = 0; it < 4; ++it) {
        int s = it * 256 + tid;
        int d = s >> 4, c = (s & 15) * 4;
        float4 g = *(const float4*)(xb + (size_t)d * Tt + c);
        *(float4*)&Ls[d][c] = g;
    }
    __syncthreads();
    const int t = tid >> 2;
    const int dseg = (tid & 3) * 16;
    Pack8 ph[2];
    float vf[16];
#pragma unroll
    for (int dd = 0; dd < 16; ++dd) {
        float v = Ls[dseg + dd][t];
        vf[dd] = v;
        ph[dd >> 3].h[dd & 7] = (__bf16)v;
    }
    size_t base = ((size_t)(b * Tt + t0 + t)) * Dd + d0 + dseg;
    *(int4*)(Xh + base)     = ph[0].v;
    *(int4*)(Xh + base + 8) = ph[1].v;
#pragma unroll
    for (int g = 0; g < 4; ++g)
        *(float4*)(Xf + base + g * 4) = make_float4(vf[g*4], vf[g*4+1], vf[g*4+2], vf[g*4+3]);
}

// ---------------- P2: emb=es/clip(u) -> Eh bf16 + embf fp32 + e2 ------------
__global__ __launch_bounds__(256) void split_e_kernel(const float* __restrict__ es,
                                                      const float* __restrict__ usage,
                                                      ushort* __restrict__ Eh,
                                                      float* __restrict__ embf,
                                                      double* __restrict__ e2d,
                                                      float* __restrict__ e2f) {
    const int wave = threadIdx.x >> 6, lane = threadIdx.x & 63;
    const int k = blockIdx.x * 4 + wave;
    const float uc = fmaxf(usage[k], EPS);
    const float* row = es + (size_t)k * Dd;
    const int d = lane * 8;
    float4 a = *(const float4*)(row + d);
    float4 c = *(const float4*)(row + d + 4);
    float ef[8] = {a.x/uc, a.y/uc, a.z/uc, a.w/uc, c.x/uc, c.y/uc, c.z/uc, c.w/uc};
    Pack8 ph;
    double e2 = 0.0;
#pragma unroll
    for (int j = 0; j < 8; ++j) {
        ph.h[j] = (__bf16)ef[j];
        e2 = fma((double)ef[j], (double)ef[j], e2);
    }
    size_t base = (size_t)k * Dd + d;
    *(int4*)(Eh + base) = ph.v;
    *(float4*)(embf + base)     = make_float4(ef[0], ef[1], ef[2], ef[3]);
    *(float4*)(embf + base + 4) = make_float4(ef[4], ef[5], ef[6], ef[7]);
#pragma unroll
    for (int off = 32; off >= 1; off >>= 1) e2 += __shfl_down(e2, off, 64);
    if (lane == 0) { e2d[k] = e2; e2f[k] = (float)e2; }
}

// ---------------- main GEMM: 256x256 tile, BK=64, cross-phase pipeline ------
// Round-6 verified K-loop. Diagnostic 4-way split: wgbase selects the
// supertile quarter; per launch 512 blocks = 8 XCD chunks of 64.
__device__ __forceinline__ void stageA2(const ushort* __restrict__ Xh, char* buf,
                                        int m0, int d0, int tid, int j0) {
#pragma unroll
    for (int j = 0; j < 2; ++j) {
        int s = (j0 + j) * 512 + tid;
        int row = s >> 3;
        int clog = (s & 7) ^ (row & 7);            // inverse swizzle on SOURCE
        gld16(Xh + (size_t)(m0 + row) * Dd + d0 + clog * 8, buf + s * 16);
    }
}
__device__ __forceinline__ void stageB2(const ushort* __restrict__ Eh, char* buf,
                                        int n0, int d0, int tid, int j0) {
#pragma unroll
    for (int j = 0; j < 2; ++j) {
        int s = (j0 + j) * 512 + tid;
        int row = s >> 3;
        int clog = (s & 7) ^ (row & 7);
        gld16(Eh + (size_t)(n0 + row) * Dd + d0 + clog * 8, buf + 32768 + s * 16);
    }
}

#define SB() __builtin_amdgcn_sched_barrier(0)

__global__ __launch_bounds__(512) void gemm_kernel(const ushort* __restrict__ Xh,
                                                   const ushort* __restrict__ Eh,
                                                   const float* __restrict__ e2f,
                                                   uint2* __restrict__ colres,
                                                   int wgbase) {
    __shared__ int4 ldsbuf[8192];   // 128 KiB
    char* lds = (char*)ldsbuf;

    const int tid = threadIdx.x;
    int wg = blockIdx.x;
    int wgid = wgbase + (wg & 7) * 64 + (wg >> 3);
    int st = wgid >> 5, u = wgid & 31;
    int mb = (st >> 3) * 8 + (u & 7);
    int nb = (st & 7) * 4 + (u >> 3);
    const int m0 = mb * 256, n0 = nb * 256;

    const int wave = tid >> 6, lane = tid & 63;
    const int wm = wave >> 1, wn = wave & 1;
    const int mw = wm * 64, nw = wn * 128;
    const int fm = lane & 15, fq = lane >> 4;
    const int fm7 = fm & 7;
    const int x0 = (fq ^ fm7) * 16;          // kk=0 swizzled chunk byte offset
    const int x1 = ((4 + fq) ^ fm7) * 16;    // kk=1
    const int pao = (mw + fm) * 128;
    const int pbo = 32768 + (nw + fm) * 128;

    f32x4 acc[8][4] = {};
    bf16x8 a0[4], a1[4], bl0[4], bh0[4], bl1[4], bh1[4];

    // prologue: tile0 full + tile1's A1; vmcnt(2) keeps A1(1) in flight
    stageA2(Xh, lds, m0, 0, tid, 0);
    stageA2(Xh, lds, m0, 0, tid, 2);
    stageB2(Eh, lds, n0, 0, tid, 0);
    stageB2(Eh, lds, n0, 0, tid, 2);
    stageA2(Xh, lds + 65536, m0, 64, tid, 0);
    asm volatile("s_waitcnt vmcnt(2)" ::: "memory");
    __builtin_amdgcn_s_barrier();
    SB();
    // S1(0) reads
#pragma unroll
    for (int i = 0; i < 4; ++i) a0[i]  = *(const bf16x8*)(lds + pao + i * 2048 + x0);
#pragma unroll
    for (int i = 0; i < 4; ++i) bl0[i] = *(const bf16x8*)(lds + pbo + i * 2048 + x0);
    SB();

    for (int t = 0; t < 8; ++t) {
        char* bufc = lds + (t & 1) * 65536;
        char* bufn = lds + ((t + 1) & 1) * 65536;
        const char* pA = bufc + pao;
        const char* pB = bufc + pbo;
        const int d1 = (t + 1) * 64, d2 = (t + 2) * 64;

        // ---- P1: issue S2 reads | stage A2(t+1) | MFMA S1 ------------------
#pragma unroll
        for (int i = 0; i < 4; ++i) bh0[i] = *(const bf16x8*)(pB + 8192 + i * 2048 + x0);
        SB();
        if (t + 1 < 8) stageA2(Xh, bufn, m0, d1, tid, 2);
        SB();
        asm volatile("s_waitcnt lgkmcnt(4)" ::: "memory");   // S1 done
        SB();
        __builtin_amdgcn_s_setprio(1);
#pragma unroll
        for (int i = 0; i < 4; ++i)
#pragma unroll
            for (int j = 0; j < 4; ++j)
                acc[i][j] = __builtin_amdgcn_mfma_f32_16x16x32_bf16(bl0[i], a0[j], acc[i][j], 0, 0, 0);
        __builtin_amdgcn_s_setprio(0);
        SB();
        __builtin_amdgcn_s_barrier();

        // ---- P2: issue S3 reads | stage B1(t+1) | MFMA S2 ------------------
#pragma unroll
        for (int i = 0; i < 4; ++i) a1[i]  = *(const bf16x8*)(pA + i * 2048 + x1);
#pragma unroll
        for (int i = 0; i < 4; ++i) bl1[i] = *(const bf16x8*)(pB + i * 2048 + x1);
        SB();
        if (t + 1 < 8) stageB2(Eh, bufn, n0, d1, tid, 0);
        SB();
        asm volatile("s_waitcnt lgkmcnt(8)" ::: "memory");   // S2 done
        SB();
        __builtin_amdgcn_s_setprio(1);
#pragma unroll
        for (int i = 0; i < 4; ++i)
#pragma unroll
            for (int j = 0; j < 4; ++j)
                acc[i + 4][j] = __builtin_amdgcn_mfma_f32_16x16x32_bf16(bh0[i], a0[j], acc[i + 4][j], 0, 0, 0);
        __builtin_amdgcn_s_setprio(0);
        SB();
        __builtin_amdgcn_s_barrier();

        // ---- P3: issue S4 reads | stage B2(t+1) | MFMA S3 ------------------
#pragma unroll
        for (int i = 0; i < 4; ++i) bh1[i] = *(const bf16x8*)(pB + 8192 + i * 2048 + x1);
        SB();
        if (t + 1 < 8) stageB2(Eh, bufn, n0, d1, tid, 2);
        SB();
        asm volatile("s_waitcnt lgkmcnt(4)" ::: "memory");   // S3 done
        SB();
        __builtin_amdgcn_s_setprio(1);
#pragma unroll
        for (int i = 0; i < 4; ++i)
#pragma unroll
            for (int j = 0; j < 4; ++j)
                acc[i][j] = __builtin_amdgcn_mfma_f32_16x16x32_bf16(bl1[i], a1[j], acc[i][j], 0, 0, 0);
        __builtin_amdgcn_s_setprio(0);
        SB();
        __builtin_amdgcn_s_barrier();

        // ---- P4: drain reads | barrier | stage A1(t+2) into bufc | MFMA S4 -
        asm volatile("s_waitcnt lgkmcnt(0)" ::: "memory");   // S4 done
        SB();
        __builtin_amdgcn_s_barrier();   // all waves' bufc reads complete
        if (t + 2 < 8) stageA2(Xh, bufc, m0, d2, tid, 0);
        SB();
        __builtin_amdgcn_s_setprio(1);
#pragma unroll
        for (int i = 0; i < 4; ++i)
#pragma unroll
            for (int j = 0; j < 4; ++j)
                acc[i + 4][j] = __builtin_amdgcn_mfma_f32_16x16x32_bf16(bh1[i], a1[j], acc[i + 4][j], 0, 0, 0);
        __builtin_amdgcn_s_setprio(0);
        SB();

        // ---- boundary: counted vmcnt + barrier + S1(t+1) reads -------------
        if (t < 7) {
            if (t < 6) { asm volatile("s_waitcnt vmcnt(2)" ::: "memory"); }
            else       { asm volatile("s_waitcnt vmcnt(0)" ::: "memory"); }
            SB();
            __builtin_amdgcn_s_barrier();
            SB();
            const char* pAn = bufn + pao;
            const char* pBn = bufn + pbo;
#pragma unroll
            for (int i = 0; i < 4; ++i) a0[i]  = *(const bf16x8*)(pAn + i * 2048 + x0);
#pragma unroll
            for (int i = 0; i < 4; ++i) bl0[i] = *(const bf16x8*)(pBn + i * 2048 + x0);
            SB();
        }
    }

    // ---- epilogue: top-2 per (m-row, 128-n-block), n lane-local ------------
    float4 e2v[8];
#pragma unroll
    for (int ni = 0; ni < 8; ++ni)
        e2v[ni] = *(const float4*)(e2f + n0 + nw + ni * 16 + fq * 4);

    const int cb = (n0 + nw) >> 7;   // 128-col block index (0..63)
#pragma unroll
    for (int mj = 0; mj < 4; ++mj) {
        unsigned s1 = 0xFFFFFFFFu, s2 = 0xFFFFFFFFu;
#pragma unroll
        for (int ni = 0; ni < 8; ++ni) {
            unsigned k0 = (monokey(fmaf(-2.0f, acc[ni][mj][0], e2v[ni].x)) & 0xFFFFFF80u) | (unsigned)(ni * 16 + fq * 4 + 0);
            unsigned k1 = (monokey(fmaf(-2.0f, acc[ni][mj][1], e2v[ni].y)) & 0xFFFFFF80u) | (unsigned)(ni * 16 + fq * 4 + 1);
            unsigned k2 = (monokey(fmaf(-2.0f, acc[ni][mj][2], e2v[ni].z)) & 0xFFFFFF80u) | (unsigned)(ni * 16 + fq * 4 + 2);
            unsigned k3 = (monokey(fmaf(-2.0f, acc[ni][mj][3], e2v[ni].w)) & 0xFFFFFF80u) | (unsigned)(ni * 16 + fq * 4 + 3);
            unsigned lo01 = min(k0, k1), hi01 = max(k0, k1);
            unsigned lo23 = min(k2, k3), hi23 = max(k2, k3);
            unsigned p1 = min(lo01, lo23);
            unsigned p2 = min(max(lo01, lo23), min(hi01, hi23));
            merge2u(s1, s2, p1, p2);
        }
#pragma unroll
        for (int stg = 16; stg <= 32; stg <<= 1) {
            unsigned b1 = __shfl_xor(s1, stg, 64);
            unsigned b2 = __shfl_xor(s2, stg, 64);
            merge2u(s1, s2, b1, b2);
        }
        if (lane < 16)
            colres[(size_t)(m0 + mw + mj * 16 + lane) * 64 + cb] = make_uint2(s1, s2);
    }
}

// ------- merge: global top-4 of block-pairs + collision ballot; tiering -----
__global__ __launch_bounds__(256) void merge_kernel(const uint2* __restrict__ colres,
                                                    float* __restrict__ out,
                                                    int* __restrict__ cnt,
                                                    int* __restrict__ queueC,
                                                    int* __restrict__ queueF) {
    const int wave = threadIdx.x >> 6, lane = threadIdx.x & 63;
    const int row = blockIdx.x * 4 + wave;
    uint2 q = colres[(size_t)row * 64 + lane];
    const unsigned nb128 = (unsigned)(lane * 128);
    u64 a1 = ((u64)(q.x & 0xFFFFFF80u) << 32) | (nb128 + (q.x & 127u));
    u64 a2 = ((u64)(q.y & 0xFFFFFF80u) << 32) | (nb128 + (q.y & 127u));
    u64 a3 = ~0ull, a4 = ~0ull;
#pragma unroll
    for (int st = 1; st < 64; st <<= 1)
        merge4q(a1, a2, a3, a4, shflx64(a1, st), shflx64(a2, st), shflx64(a3, st), shflx64(a4, st));
    // all lanes hold the global top-4 now
    float v1 = unmono((unsigned)(a1 >> 32));
    u64 coll = __ballot(unmono(q.y) < v1 + TAU);
    if (lane == 0) {
        float v2 = unmono((unsigned)(a2 >> 32));
        float v4 = unmono((unsigned)(a4 >> 32));
        int i1 = (int)(unsigned)a1;
        out[row] = (float)i1;
        if (coll != 0ull || (v4 - v1 < TAU)) {   // candidate set may be incomplete
            int p = atomicAdd(&cnt[1], 1);
            queueF[p] = row;
        } else if (v2 - v1 < TAU) {              // winner provably in {i1..i4}
            int p = atomicAdd(&cnt[0], 1);
            queueC[p * 5]     = row;
            queueC[p * 5 + 1] = i1;
            queueC[p * 5 + 2] = (int)(unsigned)a2;
            queueC[p * 5 + 3] = (int)(unsigned)a3;
            queueC[p * 5 + 4] = (int)(unsigned)a4;
        }
    }
}

// ------- candidate rescore: exact fp64 on {i1..i4}, one wave per query ------
__global__ __launch_bounds__(256) void cand_kernel(const float* __restrict__ Xf,
                                                   const float* __restrict__ embf,
                                                   const double* __restrict__ e2d,
                                                   const int* __restrict__ cnt,
                                                   const int* __restrict__ queueC,
                                                   float* __restrict__ out) {
    const int wv = (blockIdx.x << 2) | (threadIdx.x >> 6);
    const int lane = threadIdx.x & 63;
    const int n = cnt[0];
    for (int p = wv; p < n; p += gridDim.x * 4) {
        int row = queueC[p * 5];
        int ci[4] = {queueC[p*5+1], queueC[p*5+2], queueC[p*5+3], queueC[p*5+4]};
        const float* xr = Xf + (size_t)row * Dd + lane * 8;
        float4 xa = *(const float4*)xr;
        float4 xb = *(const float4*)(xr + 4);
        double s[4] = {0.0, 0.0, 0.0, 0.0};
#pragma unroll
        for (int c = 0; c < 4; ++c) {
            const float* er = embf + (size_t)ci[c] * Dd + lane * 8;
            float4 ea = *(const float4*)er;
            float4 eb = *(const float4*)(er + 4);
            double t = 0.0;
            t = fma((double)xa.x, (double)ea.x, t);
            t = fma((double)xa.y, (double)ea.y, t);
            t = fma((double)xa.z, (double)ea.z, t);
            t = fma((double)xa.w, (double)ea.w, t);
            t = fma((double)xb.x, (double)eb.x, t);
            t = fma((double)xb.y, (double)eb.y, t);
            t = fma((double)xb.z, (double)eb.z, t);
            t = fma((double)xb.w, (double)eb.w, t);
            s[c] = t;
        }
#pragma unroll
        for (int off = 32; off >= 1; off >>= 1) {
#pragma unroll
            for (int c = 0; c < 4; ++c) s[c] += __shfl_down(s[c], off, 64);
        }
        if (lane == 0) {
            double bv = DBL_MAX; int bi = 0x7fffffff;
#pragma unroll
            for (int c = 0; c < 4; ++c) {
                double dv = fma(-2.0, s[c], e2d[ci[c]]);
                if (dv < bv || (dv == bv && ci[c] < bi)) { bv = dv; bi = ci[c]; }
            }
            out[row] = (float)bi;
        }
    }
}

// -------- full exact scan v4: wave-per-row, coalesced ----------------------
// v3's thread-per-row made every wave-load touch 64 cache lines (address
// divergence; 82.5 us, VALU 15%, HBM 11% -- latency/TA-bound). v4: each wave
// owns 64 rows sequentially; per row all 64 lanes read row[lane*8..+7]
// (2 contiguous float4 wave-loads), dot vs hoisted xd[8], 6-stage fp64
// shfl tree (cand_kernel's exact pattern). Task = (qi, ch) chunk-major.
__global__ __launch_bounds__(256) void fscan_kernel(const float* __restrict__ Xf,
                                                    const float* __restrict__ embf,
                                                    const double* __restrict__ e2d,
                                                    const int* __restrict__ cnt,
                                                    const int* __restrict__ queueF,
                                                    double* __restrict__ fbv,
                                                    int* __restrict__ fbi) {
    __shared__ float xs[512];
    __shared__ double svw[4];
    __shared__ int    siw[4];
    const int tid = threadIdx.x;
    const int lane = tid & 63, wv = tid >> 6;
    const int nF = cnt[1];
    const int ntask = nF * 32;
    for (int task = blockIdx.x; task < ntask; task += gridDim.x) {
        const int ch = task / nF, qi = task - ch * nF;   // chunk-major
        const int row = queueF[qi];
        __syncthreads();
        for (int d = tid; d < Dd; d += 256)
            xs[d] = Xf[(size_t)row * Dd + d];
        __syncthreads();
        double xd[8];
#pragma unroll
        for (int j = 0; j < 8; ++j) xd[j] = (double)xs[lane * 8 + j];
        double bv = DBL_MAX; int bi = 0x7fffffff;
        const int kbase = ch * 256 + wv * 64;
#pragma unroll 2
        for (int r = 0; r < 64; ++r) {
            const int k = kbase + r;
            const float* er = embf + (size_t)k * Dd + lane * 8;
            float4 ea = *(const float4*)er;
            float4 eb = *(const float4*)(er + 4);
            double p = 0.0;
            p = fma((double)ea.x, xd[0], p);
            p = fma((double)ea.y, xd[1], p);
            p = fma((double)ea.z, xd[2], p);
            p = fma((double)ea.w, xd[3], p);
            p = fma((double)eb.x, xd[4], p);
            p = fma((double)eb.y, xd[5], p);
            p = fma((double)eb.z, xd[6], p);
            p = fma((double)eb.w, xd[7], p);
#pragma unroll
            for (int off = 32; off >= 1; off >>= 1) p += __shfl_down(p, off, 64);
            if (lane == 0) {
                double s = fma(-2.0, p, e2d[k]);
                if (s < bv || (s == bv && k < bi)) { bv = s; bi = k; }
            }
        }
        if (lane == 0) { svw[wv] = bv; siw[wv] = bi; }
        __syncthreads();
        if (tid == 0) {
            double b = svw[0]; int i = siw[0];
#pragma unroll
            for (int w2 = 1; w2 < 4; ++w2)
                if (svw[w2] < b || (svw[w2] == b && siw[w2] < i)) { b = svw[w2]; i = siw[w2]; }
            fbv[(size_t)qi * 32 + ch] = b;
            fbi[(size_t)qi * 32 + ch] = i;
        }
    }
}

__global__ void fmerge_kernel(const int* __restrict__ cnt,
                              const int* __restrict__ queueF,
                              const double* __restrict__ fbv,
                              const int* __restrict__ fbi,
                              float* __restrict__ out) {
    const int nF = cnt[1];
    for (int qi = blockIdx.x * 256 + threadIdx.x; qi < nF; qi += gridDim.x * 256) {
        double bv = DBL_MAX; int bi = 0x7fffffff;
        for (int c = 0; c < 32; ++c) {
            double v = fbv[(size_t)qi * 32 + c]; int i = fbi[(size_t)qi * 32 + c];
            if (v < bv || (v == bv && i < bi)) { bv = v; bi = i; }
        }
        out[queueF[qi]] = (float)bi;
    }
}

// ------- gather v2: LDS-staged rows (coalesced reads), coalesced-t writes ---
__global__ __launch_bounds__(256) void gather_kernel(const float* __restrict__ embf,
                                                     float* __restrict__ out) {
    __shared__ int cs[64];
    __shared__ float Ls[64][516];   // 132 KB
    const int tid = threadIdx.x;
    const int m0 = blockIdx.x * 64;
    const int b = m0 >> 10;
    const int t0 = m0 & (Tt - 1);
    if (tid < 64) cs[tid] = (int)out[m0 + tid];
    __syncthreads();
#pragma unroll
    for (int it = 0; it < 32; ++it) {
        int s = it * 256 + tid;          // 0..8191
        int r = s >> 7, f = (s & 127) * 4;
        *(float4*)&Ls[r][f] = *(const float4*)(embf + (size_t)cs[r] * Dd + f);
    }
    __syncthreads();
    const int tq = tid & 63;
    const int dg = tid >> 6;
    float* ob = out + Nq + (size_t)b * Dd * Tt + t0 + tq;
#pragma unroll 4
    for (int d = dg * 128; d < dg * 128 + 128; ++d)
        ob[(size_t)d * Tt] = Ls[tq][d];
}

extern "C" void kernel_launch(void* const* d_in, const int* in_sizes, int n_in,
                              void* d_out, int out_size, void* d_ws, size_t ws_size,
                              hipStream_t stream) {
    const float* x     = (const float*)d_in[0];
    const float* es    = (const float*)d_in[1];
    const float* usage = (const float*)d_in[2];
    float* out = (float*)d_out;

    char* w = (char*)d_ws;
    ushort* Xh = (ushort*)w;   w += (size_t)Nq * Dd * 2;      // 16 MB
    ushort* Eh = (ushort*)w;   w += (size_t)Kk * Dd * 2;      //  8 MB
    float*  Xf = (float*)w;    w += (size_t)Nq * Dd * 4;      // 32 MB
    float*  embf = (float*)w;  w += (size_t)Kk * Dd * 4;      // 16 MB
    double* e2d = (double*)w;  w += (size_t)Kk * 8;
    float*  e2f = (float*)w;   w += (size_t)Kk * 4;
    uint2* colres = (uint2*)w; w += (size_t)Nq * 64 * 8;      // 8.4 MB
    int* cnt = (int*)w;        w += 256;
    int* queueC = (int*)w;     w += (size_t)Nq * 5 * 4;
    int* queueF = (int*)w;     w += (size_t)Nq * 4;
    // fbv/fbi alias Xh (dead after gemm_kernel; fscan runs strictly later)
    double* fbv = (double*)Xh;
    int*    fbi = (int*)((char*)Xh + 8 * 1024 * 1024);

    split_x_kernel<<<2048, 256, 0, stream>>>(x, Xh, Xf, cnt);
    split_e_kernel<<<Kk / 4, 256, 0, stream>>>(es, usage, Eh, embf, e2d, e2f);
    gemm_kernel<<<512, 512, 0, stream>>>(Xh, Eh, e2f, colres, 0);
    gemm_kernel<<<512, 512, 0, stream>>>(Xh, Eh, e2f, colres, 512);
    gemm_kernel<<<512, 512, 0, stream>>>(Xh, Eh, e2f, colres, 1024);
    gemm_kernel<<<512, 512, 0, stream>>>(Xh, Eh, e2f, colres, 1536);
    merge_kernel<<<Nq / 4, 256, 0, stream>>>(colres, out, cnt, queueC, queueF);
    cand_kernel<<<256, 256, 0, stream>>>(Xf, embf, e2d, cnt, queueC, out);
    fscan_kernel<<<2048, 256, 0, stream>>>(Xf, embf, e2d, cnt, queueF, fbv, fbi);
    fmerge_kernel<<<64, 256, 0, stream>>>(cnt, queueF, fbv, fbi, out);
    gather_kernel<<<Nq / 64, 256, 0, stream>>>(embf, out);
}